// Round 5
// baseline (447.699 us; speedup 1.0000x reference)
//
#include <hip/hip_runtime.h>
#include <hip/hip_bf16.h>

typedef __bf16 bf16x8 __attribute__((ext_vector_type(8)));
typedef float f32x4 __attribute__((ext_vector_type(4)));

#define B_ 16
#define N_ 2048
#define C_ 512
#define D_ 64

__device__ __forceinline__ float bf2f(ushort u) {
    union { uint i; float f; } w; w.i = ((uint)u) << 16; return w.f;
}
__device__ __forceinline__ ushort f2bf(float f) {
    union { float f; uint i; } w; w.f = f;
    uint u = w.i;
    u = (u + 0x7fffu + ((u >> 16) & 1u)) >> 16;
    return (ushort)u;
}
__device__ __forceinline__ __bf16 u2b(ushort u) {
    union { ushort s; __bf16 b; } w; w.s = u; return w.b;
}
__device__ __forceinline__ bf16x8 ld8u(const ushort* p) { return *(const bf16x8*)p; }
__device__ __forceinline__ bf16x8 ld8f(const float* p) {
    f32x4 a = *(const f32x4*)p;
    f32x4 b = *(const f32x4*)(p + 4);
    bf16x8 r;
    r[0] = u2b(f2bf(a[0])); r[1] = u2b(f2bf(a[1]));
    r[2] = u2b(f2bf(a[2])); r[3] = u2b(f2bf(a[3]));
    r[4] = u2b(f2bf(b[0])); r[5] = u2b(f2bf(b[1]));
    r[6] = u2b(f2bf(b[2])); r[7] = u2b(f2bf(b[3]));
    return r;
}

// Decide whether float tensors are stored as f32 or bf16 (bench: f32).
__global__ void probe_kernel(const void* x, int* flag) {
    int lane = threadIdx.x & 63;
    ushort u = ((const ushort*)x)[lane * 2];
    float v = fabsf(bf2f(u));
    bool sane = (v > 9.3e-10f) && (v < 1.1e9f) && (v == v);
    unsigned long long m = __ballot(sane);
    if (threadIdx.x == 0) *flag = (__popcll(m) >= 48) ? 0 : 1;  // 0=bf16, 1=f32
}

// Merged Q+K projection: out[m, n] = sum_k X[m,k] * W{q,k}[n,k] + b{q,k}[n]
__launch_bounds__(256, 2)
__global__ void proj_qk_kernel(const void* __restrict__ X,
                               const void* __restrict__ Wq_,
                               const void* __restrict__ bq_,
                               const void* __restrict__ Wk_,
                               const void* __restrict__ bk_,
                               ushort* __restrict__ outq,
                               ushort* __restrict__ outk,
                               const int* __restrict__ flag) {
    const int isf32 = *flag;
    const ushort* Xu  = (const ushort*)X;
    const float*  Xf  = (const float*)X;
    const ushort* Wqu = (const ushort*)Wq_;
    const float*  Wqf = (const float*)Wq_;
    const ushort* Wku = (const ushort*)Wk_;
    const float*  Wkf = (const float*)Wk_;
    const ushort* Bqu = (const ushort*)bq_;
    const float*  Bqf = (const float*)bq_;
    const ushort* Bku = (const ushort*)bk_;
    const float*  Bkf = (const float*)bk_;

    __shared__ ushort lA[64][72];
    __shared__ ushort lBq[64][72];
    __shared__ ushort lBk[64][72];
    const int tid  = threadIdx.x;
    const int wave = tid >> 6, lane = tid & 63;
    const int quad = lane >> 4, li = lane & 15;
    const int m0 = blockIdx.x * 64;

    f32x4 accq[4], acck[4];
    #pragma unroll
    for (int t = 0; t < 4; ++t) {
        accq[t] = (f32x4){0.f, 0.f, 0.f, 0.f};
        acck[t] = (f32x4){0.f, 0.f, 0.f, 0.f};
    }

    for (int k0 = 0; k0 < C_; k0 += 64) {
        __syncthreads();
        #pragma unroll
        for (int it = 0; it < 2; ++it) {
            int idx = tid + it * 256;
            int row = idx >> 3, seg = idx & 7;
            size_t ea = (size_t)(m0 + row) * C_ + k0 + seg * 8;
            size_t eb = (size_t)row * C_ + k0 + seg * 8;
            if (!isf32) {
                *(bf16x8*)&lA[row][seg * 8]  = ld8u(Xu + ea);
                *(bf16x8*)&lBq[row][seg * 8] = ld8u(Wqu + eb);
                *(bf16x8*)&lBk[row][seg * 8] = ld8u(Wku + eb);
            } else {
                *(bf16x8*)&lA[row][seg * 8]  = ld8f(Xf + ea);
                *(bf16x8*)&lBq[row][seg * 8] = ld8f(Wqf + eb);
                *(bf16x8*)&lBk[row][seg * 8] = ld8f(Wkf + eb);
            }
        }
        __syncthreads();
        #pragma unroll
        for (int ks = 0; ks < 2; ++ks) {
            bf16x8 a = *(const bf16x8*)&lA[wave * 16 + li][ks * 32 + quad * 8];
            #pragma unroll
            for (int t = 0; t < 4; ++t) {
                bf16x8 bq8 = *(const bf16x8*)&lBq[t * 16 + li][ks * 32 + quad * 8];
                bf16x8 bk8 = *(const bf16x8*)&lBk[t * 16 + li][ks * 32 + quad * 8];
                accq[t] = __builtin_amdgcn_mfma_f32_16x16x32_bf16(a, bq8, accq[t], 0, 0, 0);
                acck[t] = __builtin_amdgcn_mfma_f32_16x16x32_bf16(a, bk8, acck[t], 0, 0, 0);
            }
        }
    }

    #pragma unroll
    for (int t = 0; t < 4; ++t) {
        int c = t * 16 + li;
        float bvq = isf32 ? Bqf[c] : bf2f(Bqu[c]);
        float bvk = isf32 ? Bkf[c] : bf2f(Bku[c]);
        #pragma unroll
        for (int j = 0; j < 4; ++j) {
            int m = m0 + wave * 16 + quad * 4 + j;
            outq[(size_t)m * D_ + c] = f2bf(accq[t][j] + bvq);
            outk[(size_t)m * D_ + c] = f2bf(acck[t][j] + bvk);
        }
    }
}

// Generic B^T GEMM: out[m, n] = sum_k X[m,k] * W[n,k] + bias[n]
// MODE 1: out transposed per batch (v_t  [b][c][m] bf16).
template<int NCOLS, int MODE>
__launch_bounds__(256, 2)
__global__ void proj_kernel(const void* __restrict__ X,
                            const void* __restrict__ W,
                            const void* __restrict__ bias,
                            ushort* __restrict__ out,
                            const int* __restrict__ flag,
                            size_t xoff) {
    const int isf32 = *flag;
    const ushort* Xu = (const ushort*)X + xoff;
    const float*  Xf = (const float*)X + xoff;
    const ushort* Wu = (const ushort*)W;
    const float*  Wf = (const float*)W;
    const ushort* Bu = (const ushort*)bias;
    const float*  Bf = (const float*)bias;

    __shared__ ushort lA[64][72];
    __shared__ ushort lB[64][72];
    const int tid  = threadIdx.x;
    const int wave = tid >> 6, lane = tid & 63;
    const int quad = lane >> 4, li = lane & 15;
    const int m0 = blockIdx.x * 64;
    const int n0 = blockIdx.y * 64;

    f32x4 acc[4];
    #pragma unroll
    for (int t = 0; t < 4; ++t) acc[t] = (f32x4){0.f, 0.f, 0.f, 0.f};

    for (int k0 = 0; k0 < C_; k0 += 64) {
        __syncthreads();
        #pragma unroll
        for (int it = 0; it < 2; ++it) {
            int idx = tid + it * 256;
            int row = idx >> 3, seg = idx & 7;
            size_t ea = (size_t)(m0 + row) * C_ + k0 + seg * 8;
            size_t eb = (size_t)(n0 + row) * C_ + k0 + seg * 8;
            if (!isf32) {
                *(bf16x8*)&lA[row][seg * 8] = ld8u(Xu + ea);
                *(bf16x8*)&lB[row][seg * 8] = ld8u(Wu + eb);
            } else {
                *(bf16x8*)&lA[row][seg * 8] = ld8f(Xf + ea);
                *(bf16x8*)&lB[row][seg * 8] = ld8f(Wf + eb);
            }
        }
        __syncthreads();
        #pragma unroll
        for (int ks = 0; ks < 2; ++ks) {
            bf16x8 a = *(const bf16x8*)&lA[wave * 16 + li][ks * 32 + quad * 8];
            #pragma unroll
            for (int t = 0; t < 4; ++t) {
                bf16x8 b = *(const bf16x8*)&lB[t * 16 + li][ks * 32 + quad * 8];
                acc[t] = __builtin_amdgcn_mfma_f32_16x16x32_bf16(a, b, acc[t], 0, 0, 0);
            }
        }
    }

    #pragma unroll
    for (int t = 0; t < 4; ++t) {
        int c = n0 + t * 16 + li;
        float bv = isf32 ? Bf[c] : bf2f(Bu[c]);
        if (MODE == 0) {
            #pragma unroll
            for (int j = 0; j < 4; ++j) {
                int m = m0 + wave * 16 + quad * 4 + j;
                out[(size_t)m * NCOLS + c] = f2bf(acc[t][j] + bv);
            }
        } else {
            int m = m0 + wave * 16 + quad * 4;
            int b = m >> 11, ml = m & (N_ - 1);
            ushort4 pk;
            pk.x = f2bf(acc[t][0] + bv);
            pk.y = f2bf(acc[t][1] + bv);
            pk.z = f2bf(acc[t][2] + bv);
            pk.w = f2bf(acc[t][3] + bv);
            *(ushort4*)(out + ((size_t)(b * C_ + c)) * N_ + ml) = pk;
        }
    }
}

// Fused attention (no-max softmax => no online rescaling needed):
//   per block: 64 q-rows of one batch x ALL 512 c-columns.
//   loop over 32 m-tiles (64 wide):
//     QK^T (MFMA, K frags direct from global) -> exp -> P (bf16, XOR-swizzled
//     LDS) -> PV (MFMA, V frags direct from global) accumulating O in regs.
//   l (row sums) accumulated per-lane in f32, reduced at the end.
//   epilogue: out = gamma * O / l + x.
// No S materialization, no global_load_lds (no vmcnt-drain barriers beyond
// the two P-LDS barriers). grid = 512 blocks = 2 blocks/CU, 4 waves each.
__launch_bounds__(256, 2)
__global__ void attn_fused(const ushort* __restrict__ q,
                           const ushort* __restrict__ kk,
                           const ushort* __restrict__ vt,
                           const void* __restrict__ x,
                           const void* __restrict__ gptr,
                           void* __restrict__ out,
                           const int* __restrict__ flag) {
    __shared__ ushort Pl[64 * 64];   // P tile, rows 64 x m 64, XOR-swizzled
    __shared__ float  ll[64];        // row sums

    const int tid  = threadIdx.x;
    const int wave = tid >> 6, lane = tid & 63;
    const int quad = lane >> 4, li = lane & 15;
    const int b  = blockIdx.y;
    const int q0 = blockIdx.x * 64;

    // Q fragments for this wave's P rows (q0 + wave*16 + li)
    const ushort* qrow = q + ((size_t)(b * N_ + q0 + wave * 16 + li)) * D_;
    bf16x8 qf[2];
    qf[0] = ld8u(qrow + quad * 8);
    qf[1] = ld8u(qrow + 32 + quad * 8);

    const ushort* kb = kk + (size_t)b * N_ * D_;
    const ushort* vb = vt + (size_t)b * C_ * N_;

    f32x4 acc[4][8];     // O: rows (i*16+quad*4+j) x c (wave*128 + j*16 + li)
    #pragma unroll
    for (int i = 0; i < 4; ++i)
        #pragma unroll
        for (int j = 0; j < 8; ++j) acc[i][j] = (f32x4){0.f, 0.f, 0.f, 0.f};

    f32x4 accp[4];       // P tiles tm=0..3 for rows wave*16..+16
    #pragma unroll
    for (int tm = 0; tm < 4; ++tm) accp[tm] = (f32x4){0.f, 0.f, 0.f, 0.f};
    float s4[4] = {0.f, 0.f, 0.f, 0.f};

    // prologue: QK for m-tile 0
    #pragma unroll
    for (int tm = 0; tm < 4; ++tm)
        #pragma unroll
        for (int ks = 0; ks < 2; ++ks) {
            bf16x8 kf = ld8u(kb + ((size_t)(tm * 16 + li)) * D_ + ks * 32 + quad * 8);
            accp[tm] = __builtin_amdgcn_mfma_f32_16x16x32_bf16(qf[ks], kf, accp[tm], 0, 0, 0);
        }

    for (int t = 0; t < 32; ++t) {
        __syncthreads();   // P_lds free (prev PV reads done)
        // exp(P) -> LDS (bf16, swizzled: elem at r*64 + ((m>>3)^(r&7))*8 + (m&7))
        #pragma unroll
        for (int tm = 0; tm < 4; ++tm)
            #pragma unroll
            for (int j = 0; j < 4; ++j) {
                int r = wave * 16 + quad * 4 + j;
                int m = tm * 16 + li;
                float e = __expf(fminf(accp[tm][j], 60.f));
                s4[j] += e;
                Pl[r * 64 + (((m >> 3) ^ (r & 7)) * 8) + (m & 7)] = f2bf(e);
            }
        __syncthreads();   // P ready

        // QK for m-tile t+1 (interleaves with PV below)
        if (t < 31) {
            const int m0 = (t + 1) * 64;
            #pragma unroll
            for (int tm = 0; tm < 4; ++tm) accp[tm] = (f32x4){0.f, 0.f, 0.f, 0.f};
            #pragma unroll
            for (int tm = 0; tm < 4; ++tm)
                #pragma unroll
                for (int ks = 0; ks < 2; ++ks) {
                    bf16x8 kf = ld8u(kb + ((size_t)(m0 + tm * 16 + li)) * D_ + ks * 32 + quad * 8);
                    accp[tm] = __builtin_amdgcn_mfma_f32_16x16x32_bf16(qf[ks], kf, accp[tm], 0, 0, 0);
                }
        }

        // PV for m-tile t: A = P (LDS), B = V rows c (direct global, coalesced 64B/row)
        bf16x8 af[4][2];
        #pragma unroll
        for (int i = 0; i < 4; ++i) {
            int row = i * 16 + li;
            #pragma unroll
            for (int ks = 0; ks < 2; ++ks)
                af[i][ks] = *(const bf16x8*)&Pl[row * 64 + (((ks * 4 + quad) ^ (row & 7)) * 8)];
        }
        #pragma unroll
        for (int j = 0; j < 8; ++j) {
            int c = wave * 128 + j * 16 + li;
            const ushort* vrow = vb + (size_t)c * N_ + t * 64;
            #pragma unroll
            for (int ks = 0; ks < 2; ++ks) {
                bf16x8 vf = ld8u(vrow + ks * 32 + quad * 8);
                #pragma unroll
                for (int i = 0; i < 4; ++i)
                    acc[i][j] = __builtin_amdgcn_mfma_f32_16x16x32_bf16(
                        af[i][ks], vf, acc[i][j], 0, 0, 0);
            }
        }
    }

    // reduce l across the 16 li lanes (rows quad*4+j per wave)
    #pragma unroll
    for (int j = 0; j < 4; ++j) {
        s4[j] += __shfl_xor(s4[j], 1, 64);
        s4[j] += __shfl_xor(s4[j], 2, 64);
        s4[j] += __shfl_xor(s4[j], 4, 64);
        s4[j] += __shfl_xor(s4[j], 8, 64);
    }
    if (li == 0) {
        #pragma unroll
        for (int j = 0; j < 4; ++j) ll[wave * 16 + quad * 4 + j] = s4[j];
    }
    __syncthreads();

    const int isf32 = *flag;
    const float g = isf32 ? ((const float*)gptr)[0] : bf2f(((const ushort*)gptr)[0]);
    const ushort* xu = (const ushort*)x;
    const float*  xf = (const float*)x;
    ushort* ou = (ushort*)out;
    float*  of = (float*)out;
    #pragma unroll
    for (int i = 0; i < 4; ++i)
        #pragma unroll
        for (int jj = 0; jj < 4; ++jj) {
            int nl = i * 16 + quad * 4 + jj;
            float inv = 1.f / ll[nl];
            size_t rowb = ((size_t)(b * N_ + q0 + nl)) * C_;
            #pragma unroll
            for (int j = 0; j < 8; ++j) {
                int c = wave * 128 + j * 16 + li;
                size_t idx = rowb + c;
                float xv  = isf32 ? xf[idx] : bf2f(xu[idx]);
                float val = g * (acc[i][j][jj] * inv) + xv;
                if (isf32) of[idx] = val; else ou[idx] = f2bf(val);
            }
        }
}

extern "C" void kernel_launch(void* const* d_in, const int* in_sizes, int n_in,
                              void* d_out, int out_size, void* d_ws, size_t ws_size,
                              hipStream_t stream) {
    (void)in_sizes; (void)n_in; (void)out_size; (void)ws_size;
    const void* x     = d_in[0];
    const void* Wq    = d_in[1];
    const void* bq    = d_in[2];
    const void* Wk    = d_in[3];
    const void* bk    = d_in[4];
    const void* Wv    = d_in[5];
    const void* bv    = d_in[6];
    const void* gamma = d_in[7];

    // workspace: flag(256B) + q(4M) + k(4M) + vt(32M, all batches) = ~40 MB
    int*    flag = (int*)d_ws;
    ushort* q    = (ushort*)((char*)d_ws + 256);
    ushort* kk   = q  + (size_t)B_ * N_ * D_;   // [B, N, 64] bf16
    ushort* vt   = kk + (size_t)B_ * N_ * D_;   // [B, C, N] bf16

    probe_kernel<<<1, 64, 0, stream>>>(x, flag);

    const int M = B_ * N_;  // 32768
    proj_qk_kernel<<<dim3(M / 64), 256, 0, stream>>>(x, Wq, bq, Wk, bk, q, kk, flag);
    proj_kernel<C_, 1><<<dim3(M / 64, C_ / 64), 256, 0, stream>>>(
        x, Wv, bv, vt, flag, 0);
    attn_fused<<<dim3(N_ / 64, B_), 256, 0, stream>>>(
        q, kk, vt, x, gamma, d_out, flag);
}

// Round 9
// 333.379 us; speedup vs baseline: 1.3429x; 1.3429x over previous
//
#include <hip/hip_runtime.h>
#include <hip/hip_bf16.h>

typedef __bf16 bf16x8 __attribute__((ext_vector_type(8)));
typedef float f32x4 __attribute__((ext_vector_type(4)));

#define B_ 16
#define N_ 2048
#define C_ 512
#define D_ 64

__device__ __forceinline__ float bf2f(ushort u) {
    union { uint i; float f; } w; w.i = ((uint)u) << 16; return w.f;
}
__device__ __forceinline__ ushort f2bf(float f) {
    union { float f; uint i; } w; w.f = f;
    uint u = w.i;
    u = (u + 0x7fffu + ((u >> 16) & 1u)) >> 16;
    return (ushort)u;
}
__device__ __forceinline__ __bf16 u2b(ushort u) {
    union { ushort s; __bf16 b; } w; w.s = u; return w.b;
}
__device__ __forceinline__ bf16x8 ld8u(const ushort* p) { return *(const bf16x8*)p; }
__device__ __forceinline__ bf16x8 ld8f(const float* p) {
    f32x4 a = *(const f32x4*)p;
    f32x4 b = *(const f32x4*)(p + 4);
    bf16x8 r;
    r[0] = u2b(f2bf(a[0])); r[1] = u2b(f2bf(a[1]));
    r[2] = u2b(f2bf(a[2])); r[3] = u2b(f2bf(a[3]));
    r[4] = u2b(f2bf(b[0])); r[5] = u2b(f2bf(b[1]));
    r[6] = u2b(f2bf(b[2])); r[7] = u2b(f2bf(b[3]));
    return r;
}

// async global->LDS, 16 B per lane; LDS dest = wave-uniform base + lane*16
__device__ __forceinline__ void gload16(const ushort* g, ushort* l) {
    __builtin_amdgcn_global_load_lds(
        (const __attribute__((address_space(1))) void*)g,
        (__attribute__((address_space(3))) void*)l, 16, 0, 0);
}

// Decide whether float tensors are stored as f32 or bf16 (bench: f32).
__global__ void probe_kernel(const void* x, int* flag) {
    int lane = threadIdx.x & 63;
    ushort u = ((const ushort*)x)[lane * 2];
    float v = fabsf(bf2f(u));
    bool sane = (v > 9.3e-10f) && (v < 1.1e9f) && (v == v);
    unsigned long long m = __ballot(sane);
    if (threadIdx.x == 0) *flag = (__popcll(m) >= 48) ? 0 : 1;  // 0=bf16, 1=f32
}

// Merged Q+K projection: out[m, n] = sum_k X[m,k] * W{q,k}[n,k] + b{q,k}[n]
__launch_bounds__(256, 2)
__global__ void proj_qk_kernel(const void* __restrict__ X,
                               const void* __restrict__ Wq_,
                               const void* __restrict__ bq_,
                               const void* __restrict__ Wk_,
                               const void* __restrict__ bk_,
                               ushort* __restrict__ outq,
                               ushort* __restrict__ outk,
                               const int* __restrict__ flag) {
    const int isf32 = *flag;
    const ushort* Xu  = (const ushort*)X;
    const float*  Xf  = (const float*)X;
    const ushort* Wqu = (const ushort*)Wq_;
    const float*  Wqf = (const float*)Wq_;
    const ushort* Wku = (const ushort*)Wk_;
    const float*  Wkf = (const float*)Wk_;
    const ushort* Bqu = (const ushort*)bq_;
    const float*  Bqf = (const float*)bq_;
    const ushort* Bku = (const ushort*)bk_;
    const float*  Bkf = (const float*)bk_;

    __shared__ ushort lA[64][72];
    __shared__ ushort lBq[64][72];
    __shared__ ushort lBk[64][72];
    const int tid  = threadIdx.x;
    const int wave = tid >> 6, lane = tid & 63;
    const int quad = lane >> 4, li = lane & 15;
    const int m0 = blockIdx.x * 64;

    f32x4 accq[4], acck[4];
    #pragma unroll
    for (int t = 0; t < 4; ++t) {
        accq[t] = (f32x4){0.f, 0.f, 0.f, 0.f};
        acck[t] = (f32x4){0.f, 0.f, 0.f, 0.f};
    }

    for (int k0 = 0; k0 < C_; k0 += 64) {
        __syncthreads();
        #pragma unroll
        for (int it = 0; it < 2; ++it) {
            int idx = tid + it * 256;
            int row = idx >> 3, seg = idx & 7;
            size_t ea = (size_t)(m0 + row) * C_ + k0 + seg * 8;
            size_t eb = (size_t)row * C_ + k0 + seg * 8;
            if (!isf32) {
                *(bf16x8*)&lA[row][seg * 8]  = ld8u(Xu + ea);
                *(bf16x8*)&lBq[row][seg * 8] = ld8u(Wqu + eb);
                *(bf16x8*)&lBk[row][seg * 8] = ld8u(Wku + eb);
            } else {
                *(bf16x8*)&lA[row][seg * 8]  = ld8f(Xf + ea);
                *(bf16x8*)&lBq[row][seg * 8] = ld8f(Wqf + eb);
                *(bf16x8*)&lBk[row][seg * 8] = ld8f(Wkf + eb);
            }
        }
        __syncthreads();
        #pragma unroll
        for (int ks = 0; ks < 2; ++ks) {
            bf16x8 a = *(const bf16x8*)&lA[wave * 16 + li][ks * 32 + quad * 8];
            #pragma unroll
            for (int t = 0; t < 4; ++t) {
                bf16x8 bq8 = *(const bf16x8*)&lBq[t * 16 + li][ks * 32 + quad * 8];
                bf16x8 bk8 = *(const bf16x8*)&lBk[t * 16 + li][ks * 32 + quad * 8];
                accq[t] = __builtin_amdgcn_mfma_f32_16x16x32_bf16(a, bq8, accq[t], 0, 0, 0);
                acck[t] = __builtin_amdgcn_mfma_f32_16x16x32_bf16(a, bk8, acck[t], 0, 0, 0);
            }
        }
    }

    #pragma unroll
    for (int t = 0; t < 4; ++t) {
        int c = t * 16 + li;
        float bvq = isf32 ? Bqf[c] : bf2f(Bqu[c]);
        float bvk = isf32 ? Bkf[c] : bf2f(Bku[c]);
        #pragma unroll
        for (int j = 0; j < 4; ++j) {
            int m = m0 + wave * 16 + quad * 4 + j;
            outq[(size_t)m * D_ + c] = f2bf(accq[t][j] + bvq);
            outk[(size_t)m * D_ + c] = f2bf(acck[t][j] + bvk);
        }
    }
}

// Generic B^T GEMM: out[m, n] = sum_k X[m,k] * W[n,k] + bias[n]
// MODE 1: out transposed per batch (v_t  [b][c][m] bf16).
template<int NCOLS, int MODE>
__launch_bounds__(256, 2)
__global__ void proj_kernel(const void* __restrict__ X,
                            const void* __restrict__ W,
                            const void* __restrict__ bias,
                            ushort* __restrict__ out,
                            const int* __restrict__ flag,
                            size_t xoff) {
    const int isf32 = *flag;
    const ushort* Xu = (const ushort*)X + xoff;
    const float*  Xf = (const float*)X + xoff;
    const ushort* Wu = (const ushort*)W;
    const float*  Wf = (const float*)W;
    const ushort* Bu = (const ushort*)bias;
    const float*  Bf = (const float*)bias;

    __shared__ ushort lA[64][72];
    __shared__ ushort lB[64][72];
    const int tid  = threadIdx.x;
    const int wave = tid >> 6, lane = tid & 63;
    const int quad = lane >> 4, li = lane & 15;
    const int m0 = blockIdx.x * 64;
    const int n0 = blockIdx.y * 64;

    f32x4 acc[4];
    #pragma unroll
    for (int t = 0; t < 4; ++t) acc[t] = (f32x4){0.f, 0.f, 0.f, 0.f};

    for (int k0 = 0; k0 < C_; k0 += 64) {
        __syncthreads();
        #pragma unroll
        for (int it = 0; it < 2; ++it) {
            int idx = tid + it * 256;
            int row = idx >> 3, seg = idx & 7;
            size_t ea = (size_t)(m0 + row) * C_ + k0 + seg * 8;
            size_t eb = (size_t)(n0 + row) * C_ + k0 + seg * 8;
            if (!isf32) {
                *(bf16x8*)&lA[row][seg * 8] = ld8u(Xu + ea);
                *(bf16x8*)&lB[row][seg * 8] = ld8u(Wu + eb);
            } else {
                *(bf16x8*)&lA[row][seg * 8] = ld8f(Xf + ea);
                *(bf16x8*)&lB[row][seg * 8] = ld8f(Wf + eb);
            }
        }
        __syncthreads();
        #pragma unroll
        for (int ks = 0; ks < 2; ++ks) {
            bf16x8 a = *(const bf16x8*)&lA[wave * 16 + li][ks * 32 + quad * 8];
            #pragma unroll
            for (int t = 0; t < 4; ++t) {
                bf16x8 b = *(const bf16x8*)&lB[t * 16 + li][ks * 32 + quad * 8];
                acc[t] = __builtin_amdgcn_mfma_f32_16x16x32_bf16(a, b, acc[t], 0, 0, 0);
            }
        }
    }

    #pragma unroll
    for (int t = 0; t < 4; ++t) {
        int c = n0 + t * 16 + li;
        float bv = isf32 ? Bf[c] : bf2f(Bu[c]);
        if (MODE == 0) {
            #pragma unroll
            for (int j = 0; j < 4; ++j) {
                int m = m0 + wave * 16 + quad * 4 + j;
                out[(size_t)m * NCOLS + c] = f2bf(acc[t][j] + bv);
            }
        } else {
            int m = m0 + wave * 16 + quad * 4;
            int b = m >> 11, ml = m & (N_ - 1);
            ushort4 pk;
            pk.x = f2bf(acc[t][0] + bv);
            pk.y = f2bf(acc[t][1] + bv);
            pk.z = f2bf(acc[t][2] + bv);
            pk.w = f2bf(acc[t][3] + bv);
            *(ushort4*)(out + ((size_t)(b * C_ + c)) * N_ + ml) = pk;
        }
    }
}

// Fused attention v2 (no-max softmax => no online rescaling):
//   block = 64 q-rows x 256 c-cols of one batch (grid 32 x 2 x 16), 8 waves.
//   wave w: q-half wq=w&1 (32 rows), wm=w>>1 (16-wide m-range for QK,
//   64-wide c-range for PV).
//   Per m-tile t (64 wide):
//     stage V(t) [256x64] and K(t+1) [64x64] via global_load_lds into
//     XOR-swizzled LDS; write P(t)=exp(accp) to swizzled LDS; barrier;
//     QK(t+1) from K LDS -> accp; PV(t) from P,V LDS -> acc (regs).
//   QK is duplicated across the 2 c-half blocks (cheap: +8.6 GF total).
//   l: per-lane partial sums -> shfl reduce -> LDS atomicAdd across waves.
//   epilogue: out = gamma * O / l + x.
// Register budget: acc[2][4]=32 + accp 8 + qf 16 + misc ~ <=128 unified
// -> 4 waves/SIMD (16 waves/CU) via __launch_bounds__(512, 4).
__launch_bounds__(512, 4)
__global__ void attn_fused(const ushort* __restrict__ q,
                           const ushort* __restrict__ kk,
                           const ushort* __restrict__ vt,
                           const void* __restrict__ x,
                           const void* __restrict__ gptr,
                           void* __restrict__ out,
                           const int* __restrict__ flag) {
    __shared__ ushort Pl[64 * 64];    //  8 KB P tile (swizzled)
    __shared__ ushort Vl[256 * 64];   // 32 KB V tile (swizzled, rows=c)
    __shared__ ushort Kl[64 * 64];    //  8 KB K(t+1) tile (swizzled)
    __shared__ float  ll[64];         // row sums

    const int tid  = threadIdx.x;
    const int wave = tid >> 6, lane = tid & 63;
    const int quad = lane >> 4, li = lane & 15;
    const int wq = wave & 1;          // q-half (32 rows)
    const int wm = wave >> 1;         // 16-wide m-range (QK) / 64-wide c-range (PV)
    const int b  = blockIdx.z;
    const int q0 = blockIdx.x * 64;
    const int c0 = blockIdx.y * 256;

    const ushort* kb = kk + (size_t)b * N_ * D_;
    const ushort* vb = vt + ((size_t)b * C_ + c0) * N_;

    // staging lane constants (pre-swizzled global source -> linear LDS dest)
    const int lrow8 = lane >> 3;               // 0..7
    const int lseg  = (lane & 7) ^ lrow8;      // XOR'd 16B granule

    // Q fragments: rows q0 + wq*32 + i*16 + li
    bf16x8 qf[2][2];
    #pragma unroll
    for (int i = 0; i < 2; ++i)
        #pragma unroll
        for (int ks = 0; ks < 2; ++ks)
            qf[i][ks] = ld8u(q + ((size_t)(b * N_ + q0 + wq * 32 + i * 16 + li)) * D_
                               + ks * 32 + quad * 8);

    f32x4 acc[2][4];   // O rows wq*32+i*16+quad*4+jj, cols c0+wm*64+j*16+li
    #pragma unroll
    for (int i = 0; i < 2; ++i)
        #pragma unroll
        for (int j = 0; j < 4; ++j) acc[i][j] = (f32x4){0.f, 0.f, 0.f, 0.f};

    f32x4 accp[2];     // P rows wq*32+i*16+quad*4+j, m col wm*16+li
    float s4[2][4];
    #pragma unroll
    for (int i = 0; i < 2; ++i) {
        accp[i] = (f32x4){0.f, 0.f, 0.f, 0.f};
        #pragma unroll
        for (int j = 0; j < 4; ++j) s4[i][j] = 0.f;
    }

    // prologue: QK(0) with direct K loads (once; in-loop K comes from LDS)
    #pragma unroll
    for (int ks = 0; ks < 2; ++ks) {
        bf16x8 kf = ld8u(kb + ((size_t)(wm * 16 + li)) * D_ + ks * 32 + quad * 8);
        #pragma unroll
        for (int i = 0; i < 2; ++i)
            accp[i] = __builtin_amdgcn_mfma_f32_16x16x32_bf16(qf[i][ks], kf, accp[i], 0, 0, 0);
    }

    for (int t = 0; t < 32; ++t) {
        __syncthreads();   // prev compute done reading Pl/Vl/Kl
        // stage V(t): 256 rows x 128 B; each wave 4 instrs x 8 rows
        #pragma unroll
        for (int it = 0; it < 4; ++it) {
            int rbase = wave * 32 + it * 8;
            gload16(vb + (size_t)(rbase + lrow8) * N_ + t * 64 + lseg * 8,
                    &Vl[rbase * 64]);
        }
        // stage K(t+1): 64 rows x 128 B; 1 instr per wave
        if (t < 31) {
            int rbase = wave * 8;
            gload16(kb + (size_t)((t + 1) * 64 + rbase + lrow8) * D_ + lseg * 8,
                    &Kl[rbase * 64]);
        }
        // write P(t) = exp(accp) -> swizzled LDS; accumulate row sums
        #pragma unroll
        for (int i = 0; i < 2; ++i)
            #pragma unroll
            for (int j = 0; j < 4; ++j) {
                int r = wq * 32 + i * 16 + quad * 4 + j;
                int m = wm * 16 + li;
                float e = __expf(fminf(accp[i][j], 60.f));
                s4[i][j] += e;
                Pl[r * 64 + (((m >> 3) ^ (r & 7)) * 8) + (m & 7)] = f2bf(e);
            }
        __syncthreads();   // drains DMA (vmcnt) + P writes: tiles ready

        // QK(t+1) from Kl
        if (t < 31) {
            #pragma unroll
            for (int i = 0; i < 2; ++i) accp[i] = (f32x4){0.f, 0.f, 0.f, 0.f};
            #pragma unroll
            for (int ks = 0; ks < 2; ++ks) {
                bf16x8 kf = *(const bf16x8*)&Kl[(wm * 16 + li) * 64
                                                + (((ks * 4 + quad) ^ (li & 7)) * 8)];
                #pragma unroll
                for (int i = 0; i < 2; ++i)
                    accp[i] = __builtin_amdgcn_mfma_f32_16x16x32_bf16(
                        qf[i][ks], kf, accp[i], 0, 0, 0);
            }
        }

        // PV(t): A = P rows (wq half), B = V rows c (wm range)
        #pragma unroll
        for (int ks = 0; ks < 2; ++ks) {
            bf16x8 af[2];
            #pragma unroll
            for (int i = 0; i < 2; ++i)
                af[i] = *(const bf16x8*)&Pl[(wq * 32 + i * 16 + li) * 64
                                            + (((ks * 4 + quad) ^ (li & 7)) * 8)];
            #pragma unroll
            for (int j = 0; j < 4; ++j) {
                bf16x8 vf = *(const bf16x8*)&Vl[(wm * 64 + j * 16 + li) * 64
                                                + (((ks * 4 + quad) ^ (li & 7)) * 8)];
                #pragma unroll
                for (int i = 0; i < 2; ++i)
                    acc[i][j] = __builtin_amdgcn_mfma_f32_16x16x32_bf16(
                        af[i], vf, acc[i][j], 0, 0, 0);
            }
        }
    }

    // l reduction: shfl over the 16 li lanes, then add the 4 wm-partner waves
    __syncthreads();
    if (tid < 64) ll[tid] = 0.f;
    __syncthreads();
    #pragma unroll
    for (int i = 0; i < 2; ++i)
        #pragma unroll
        for (int j = 0; j < 4; ++j) {
            float s = s4[i][j];
            s += __shfl_xor(s, 1, 64);
            s += __shfl_xor(s, 2, 64);
            s += __shfl_xor(s, 4, 64);
            s += __shfl_xor(s, 8, 64);
            if (li == 0) atomicAdd(&ll[wq * 32 + i * 16 + quad * 4 + j], s);
        }
    __syncthreads();

    const int isf32 = *flag;
    const float g = isf32 ? ((const float*)gptr)[0] : bf2f(((const ushort*)gptr)[0]);
    const ushort* xu = (const ushort*)x;
    const float*  xf = (const float*)x;
    ushort* ou = (ushort*)out;
    float*  of = (float*)out;
    #pragma unroll
    for (int i = 0; i < 2; ++i)
        #pragma unroll
        for (int jj = 0; jj < 4; ++jj) {
            int nl = wq * 32 + i * 16 + quad * 4 + jj;
            float inv = 1.f / ll[nl];
            size_t rowb = ((size_t)(b * N_ + q0 + nl)) * C_;
            #pragma unroll
            for (int j = 0; j < 4; ++j) {
                int cg = c0 + wm * 64 + j * 16 + li;
                size_t idx = rowb + cg;
                float xv  = isf32 ? xf[idx] : bf2f(xu[idx]);
                float val = g * (acc[i][j][jj] * inv) + xv;
                if (isf32) of[idx] = val; else ou[idx] = f2bf(val);
            }
        }
}

extern "C" void kernel_launch(void* const* d_in, const int* in_sizes, int n_in,
                              void* d_out, int out_size, void* d_ws, size_t ws_size,
                              hipStream_t stream) {
    (void)in_sizes; (void)n_in; (void)out_size; (void)ws_size;
    const void* x     = d_in[0];
    const void* Wq    = d_in[1];
    const void* bq    = d_in[2];
    const void* Wk    = d_in[3];
    const void* bk    = d_in[4];
    const void* Wv    = d_in[5];
    const void* bv    = d_in[6];
    const void* gamma = d_in[7];

    // workspace: flag(256B) + q(4M) + k(4M) + vt(32M, all batches) = ~40 MB
    int*    flag = (int*)d_ws;
    ushort* q    = (ushort*)((char*)d_ws + 256);
    ushort* kk   = q  + (size_t)B_ * N_ * D_;   // [B, N, 64] bf16
    ushort* vt   = kk + (size_t)B_ * N_ * D_;   // [B, C, N] bf16

    probe_kernel<<<1, 64, 0, stream>>>(x, flag);

    const int M = B_ * N_;  // 32768
    proj_qk_kernel<<<dim3(M / 64), 256, 0, stream>>>(x, Wq, bq, Wk, bk, q, kk, flag);
    proj_kernel<C_, 1><<<dim3(M / 64, C_ / 64), 256, 0, stream>>>(
        x, Wv, bv, vt, flag, 0);
    attn_fused<<<dim3(N_ / 64, 2, B_), 512, 0, stream>>>(
        q, kk, vt, x, gamma, d_out, flag);
}

// Round 10
// 330.117 us; speedup vs baseline: 1.3562x; 1.0099x over previous
//
#include <hip/hip_runtime.h>
#include <hip/hip_bf16.h>

typedef __bf16 bf16x8 __attribute__((ext_vector_type(8)));
typedef float f32x4 __attribute__((ext_vector_type(4)));

#define B_ 16
#define N_ 2048
#define C_ 512
#define D_ 64

__device__ __forceinline__ float bf2f(ushort u) {
    union { uint i; float f; } w; w.i = ((uint)u) << 16; return w.f;
}
__device__ __forceinline__ ushort f2bf(float f) {
    union { float f; uint i; } w; w.f = f;
    uint u = w.i;
    u = (u + 0x7fffu + ((u >> 16) & 1u)) >> 16;
    return (ushort)u;
}
__device__ __forceinline__ __bf16 u2b(ushort u) {
    union { ushort s; __bf16 b; } w; w.s = u; return w.b;
}
__device__ __forceinline__ bf16x8 ld8u(const ushort* p) { return *(const bf16x8*)p; }
__device__ __forceinline__ bf16x8 ld8f(const float* p) {
    f32x4 a = *(const f32x4*)p;
    f32x4 b = *(const f32x4*)(p + 4);
    bf16x8 r;
    r[0] = u2b(f2bf(a[0])); r[1] = u2b(f2bf(a[1]));
    r[2] = u2b(f2bf(a[2])); r[3] = u2b(f2bf(a[3]));
    r[4] = u2b(f2bf(b[0])); r[5] = u2b(f2bf(b[1]));
    r[6] = u2b(f2bf(b[2])); r[7] = u2b(f2bf(b[3]));
    return r;
}

// async global->LDS, 16 B per lane; LDS dest = wave-uniform base + lane*16
__device__ __forceinline__ void gload16(const ushort* g, ushort* l) {
    __builtin_amdgcn_global_load_lds(
        (const __attribute__((address_space(1))) void*)g,
        (__attribute__((address_space(3))) void*)l, 16, 0, 0);
}

// Decide whether float tensors are stored as f32 or bf16 (bench: f32).
__global__ void probe_kernel(const void* x, int* flag) {
    int lane = threadIdx.x & 63;
    ushort u = ((const ushort*)x)[lane * 2];
    float v = fabsf(bf2f(u));
    bool sane = (v > 9.3e-10f) && (v < 1.1e9f) && (v == v);
    unsigned long long m = __ballot(sane);
    if (threadIdx.x == 0) *flag = (__popcll(m) >= 48) ? 0 : 1;  // 0=bf16, 1=f32
}

// Merged Q+K projection: out[m, n] = sum_k X[m,k] * W{q,k}[n,k] + b{q,k}[n]
__launch_bounds__(256, 2)
__global__ void proj_qk_kernel(const void* __restrict__ X,
                               const void* __restrict__ Wq_,
                               const void* __restrict__ bq_,
                               const void* __restrict__ Wk_,
                               const void* __restrict__ bk_,
                               ushort* __restrict__ outq,
                               ushort* __restrict__ outk,
                               const int* __restrict__ flag) {
    const int isf32 = *flag;
    const ushort* Xu  = (const ushort*)X;
    const float*  Xf  = (const float*)X;
    const ushort* Wqu = (const ushort*)Wq_;
    const float*  Wqf = (const float*)Wq_;
    const ushort* Wku = (const ushort*)Wk_;
    const float*  Wkf = (const float*)Wk_;
    const ushort* Bqu = (const ushort*)bq_;
    const float*  Bqf = (const float*)bq_;
    const ushort* Bku = (const ushort*)bk_;
    const float*  Bkf = (const float*)bk_;

    __shared__ ushort lA[64][72];
    __shared__ ushort lBq[64][72];
    __shared__ ushort lBk[64][72];
    const int tid  = threadIdx.x;
    const int wave = tid >> 6, lane = tid & 63;
    const int quad = lane >> 4, li = lane & 15;
    const int m0 = blockIdx.x * 64;

    f32x4 accq[4], acck[4];
    #pragma unroll
    for (int t = 0; t < 4; ++t) {
        accq[t] = (f32x4){0.f, 0.f, 0.f, 0.f};
        acck[t] = (f32x4){0.f, 0.f, 0.f, 0.f};
    }

    for (int k0 = 0; k0 < C_; k0 += 64) {
        __syncthreads();
        #pragma unroll
        for (int it = 0; it < 2; ++it) {
            int idx = tid + it * 256;
            int row = idx >> 3, seg = idx & 7;
            size_t ea = (size_t)(m0 + row) * C_ + k0 + seg * 8;
            size_t eb = (size_t)row * C_ + k0 + seg * 8;
            if (!isf32) {
                *(bf16x8*)&lA[row][seg * 8]  = ld8u(Xu + ea);
                *(bf16x8*)&lBq[row][seg * 8] = ld8u(Wqu + eb);
                *(bf16x8*)&lBk[row][seg * 8] = ld8u(Wku + eb);
            } else {
                *(bf16x8*)&lA[row][seg * 8]  = ld8f(Xf + ea);
                *(bf16x8*)&lBq[row][seg * 8] = ld8f(Wqf + eb);
                *(bf16x8*)&lBk[row][seg * 8] = ld8f(Wkf + eb);
            }
        }
        __syncthreads();
        #pragma unroll
        for (int ks = 0; ks < 2; ++ks) {
            bf16x8 a = *(const bf16x8*)&lA[wave * 16 + li][ks * 32 + quad * 8];
            #pragma unroll
            for (int t = 0; t < 4; ++t) {
                bf16x8 bq8 = *(const bf16x8*)&lBq[t * 16 + li][ks * 32 + quad * 8];
                bf16x8 bk8 = *(const bf16x8*)&lBk[t * 16 + li][ks * 32 + quad * 8];
                accq[t] = __builtin_amdgcn_mfma_f32_16x16x32_bf16(a, bq8, accq[t], 0, 0, 0);
                acck[t] = __builtin_amdgcn_mfma_f32_16x16x32_bf16(a, bk8, acck[t], 0, 0, 0);
            }
        }
    }

    #pragma unroll
    for (int t = 0; t < 4; ++t) {
        int c = t * 16 + li;
        float bvq = isf32 ? Bqf[c] : bf2f(Bqu[c]);
        float bvk = isf32 ? Bkf[c] : bf2f(Bku[c]);
        #pragma unroll
        for (int j = 0; j < 4; ++j) {
            int m = m0 + wave * 16 + quad * 4 + j;
            outq[(size_t)m * D_ + c] = f2bf(accq[t][j] + bvq);
            outk[(size_t)m * D_ + c] = f2bf(acck[t][j] + bvk);
        }
    }
}

// Generic B^T GEMM: out[m, n] = sum_k X[m,k] * W[n,k] + bias[n]
// MODE 1: out transposed per batch (v_t  [b][c][m] bf16).
template<int NCOLS, int MODE>
__launch_bounds__(256, 2)
__global__ void proj_kernel(const void* __restrict__ X,
                            const void* __restrict__ W,
                            const void* __restrict__ bias,
                            ushort* __restrict__ out,
                            const int* __restrict__ flag,
                            size_t xoff) {
    const int isf32 = *flag;
    const ushort* Xu = (const ushort*)X + xoff;
    const float*  Xf = (const float*)X + xoff;
    const ushort* Wu = (const ushort*)W;
    const float*  Wf = (const float*)W;
    const ushort* Bu = (const ushort*)bias;
    const float*  Bf = (const float*)bias;

    __shared__ ushort lA[64][72];
    __shared__ ushort lB[64][72];
    const int tid  = threadIdx.x;
    const int wave = tid >> 6, lane = tid & 63;
    const int quad = lane >> 4, li = lane & 15;
    const int m0 = blockIdx.x * 64;
    const int n0 = blockIdx.y * 64;

    f32x4 acc[4];
    #pragma unroll
    for (int t = 0; t < 4; ++t) acc[t] = (f32x4){0.f, 0.f, 0.f, 0.f};

    for (int k0 = 0; k0 < C_; k0 += 64) {
        __syncthreads();
        #pragma unroll
        for (int it = 0; it < 2; ++it) {
            int idx = tid + it * 256;
            int row = idx >> 3, seg = idx & 7;
            size_t ea = (size_t)(m0 + row) * C_ + k0 + seg * 8;
            size_t eb = (size_t)(n0 + row) * C_ + k0 + seg * 8;
            if (!isf32) {
                *(bf16x8*)&lA[row][seg * 8] = ld8u(Xu + ea);
                *(bf16x8*)&lB[row][seg * 8] = ld8u(Wu + eb);
            } else {
                *(bf16x8*)&lA[row][seg * 8] = ld8f(Xf + ea);
                *(bf16x8*)&lB[row][seg * 8] = ld8f(Wf + eb);
            }
        }
        __syncthreads();
        #pragma unroll
        for (int ks = 0; ks < 2; ++ks) {
            bf16x8 a = *(const bf16x8*)&lA[wave * 16 + li][ks * 32 + quad * 8];
            #pragma unroll
            for (int t = 0; t < 4; ++t) {
                bf16x8 b = *(const bf16x8*)&lB[t * 16 + li][ks * 32 + quad * 8];
                acc[t] = __builtin_amdgcn_mfma_f32_16x16x32_bf16(a, b, acc[t], 0, 0, 0);
            }
        }
    }

    #pragma unroll
    for (int t = 0; t < 4; ++t) {
        int c = n0 + t * 16 + li;
        float bv = isf32 ? Bf[c] : bf2f(Bu[c]);
        if (MODE == 0) {
            #pragma unroll
            for (int j = 0; j < 4; ++j) {
                int m = m0 + wave * 16 + quad * 4 + j;
                out[(size_t)m * NCOLS + c] = f2bf(acc[t][j] + bv);
            }
        } else {
            int m = m0 + wave * 16 + quad * 4;
            int b = m >> 11, ml = m & (N_ - 1);
            ushort4 pk;
            pk.x = f2bf(acc[t][0] + bv);
            pk.y = f2bf(acc[t][1] + bv);
            pk.z = f2bf(acc[t][2] + bv);
            pk.w = f2bf(acc[t][3] + bv);
            *(ushort4*)(out + ((size_t)(b * C_ + c)) * N_ + ml) = pk;
        }
    }
}

// Fused attention v3: v2 + double-buffered V with counted-vmcnt raw barriers
// (T3/T4-lite) + K register prefetch + setprio around PV (T5).
//   block = 64 q-rows x 256 c-cols (grid 32 x 2 x 16), 8 waves, 512 thr.
//   Pipeline per m-tile t:
//     issue V(t+1)->Vl[buf^1] (4 gload16)  -- stays in flight across barrier
//     P-write(t) = exp(accp) -> Pl (VALU)
//     QK(t+1) = mfma(qf, kreg) ; prefetch kreg(t+2) (2 global loads)
//     s_waitcnt vmcnt(6) lgkmcnt(0)  -- drains V(t) + P-writes, leaves 6 in flight
//     s_barrier ; PV(t) from Pl,Vl[buf] ; s_barrier
//   vmcnt count: iter-t issues exactly 6 VMEM ops (4 V + 2 kreg), pinned
//   before the asm by the "memory" clobber -> vmcnt(6) provably drains V(t).
//   Tail: vmcnt(4) at t=30 (no kreg), vmcnt(0) at t=31 (no stage).
// LDS = 2x32K (V) + 8K (P) + ll = 72.5 KB -> 2 blocks/CU, 16 waves/CU.
__launch_bounds__(512, 4)
__global__ void attn_fused(const ushort* __restrict__ q,
                           const ushort* __restrict__ kk,
                           const ushort* __restrict__ vt,
                           const void* __restrict__ x,
                           const void* __restrict__ gptr,
                           void* __restrict__ out,
                           const int* __restrict__ flag) {
    __shared__ ushort Vl[2][256 * 64];   // 2 x 32 KB V tile (swizzled, rows=c)
    __shared__ ushort Pl[64 * 64];       //  8 KB P tile (swizzled)
    __shared__ float  ll[64];            // row sums

    const int tid  = threadIdx.x;
    const int wave = tid >> 6, lane = tid & 63;
    const int quad = lane >> 4, li = lane & 15;
    const int wq = wave & 1;          // q-half (32 rows)
    const int wm = wave >> 1;         // 16-wide m-range (QK) / 64-wide c-range (PV)
    const int b  = blockIdx.z;
    const int q0 = blockIdx.x * 64;
    const int c0 = blockIdx.y * 256;

    const ushort* kb = kk + (size_t)b * N_ * D_;
    const ushort* vb = vt + ((size_t)b * C_ + c0) * N_;

    // staging lane constants (pre-swizzled global source -> linear LDS dest)
    const int lrow8 = lane >> 3;               // 0..7
    const int lseg  = (lane & 7) ^ lrow8;      // XOR'd 16B granule

    // Q fragments: rows q0 + wq*32 + i*16 + li
    bf16x8 qf[2][2];
    #pragma unroll
    for (int i = 0; i < 2; ++i)
        #pragma unroll
        for (int ks = 0; ks < 2; ++ks)
            qf[i][ks] = ld8u(q + ((size_t)(b * N_ + q0 + wq * 32 + i * 16 + li)) * D_
                               + ks * 32 + quad * 8);

    f32x4 acc[2][4];   // O rows wq*32+i*16+quad*4+jj, cols c0+wm*64+j*16+li
    #pragma unroll
    for (int i = 0; i < 2; ++i)
        #pragma unroll
        for (int j = 0; j < 4; ++j) acc[i][j] = (f32x4){0.f, 0.f, 0.f, 0.f};

    f32x4 accp[2];     // P rows wq*32+i*16+quad*4+j, m col wm*16+li
    float s4[2][4];
    #pragma unroll
    for (int i = 0; i < 2; ++i) {
        accp[i] = (f32x4){0.f, 0.f, 0.f, 0.f};
        #pragma unroll
        for (int j = 0; j < 4; ++j) s4[i][j] = 0.f;
    }

    // prologue: stage V(0) -> Vl[0]; QK(0) with direct K loads; kreg = K(1)
    #pragma unroll
    for (int it = 0; it < 4; ++it) {
        int rbase = wave * 32 + it * 8;
        gload16(vb + (size_t)(rbase + lrow8) * N_ + lseg * 8, &Vl[0][rbase * 64]);
    }
    {
        bf16x8 k0 = ld8u(kb + (size_t)(wm * 16 + li) * D_ + quad * 8);
        bf16x8 k1 = ld8u(kb + (size_t)(wm * 16 + li) * D_ + 32 + quad * 8);
        accp[0] = __builtin_amdgcn_mfma_f32_16x16x32_bf16(qf[0][0], k0, accp[0], 0, 0, 0);
        accp[1] = __builtin_amdgcn_mfma_f32_16x16x32_bf16(qf[1][0], k0, accp[1], 0, 0, 0);
        accp[0] = __builtin_amdgcn_mfma_f32_16x16x32_bf16(qf[0][1], k1, accp[0], 0, 0, 0);
        accp[1] = __builtin_amdgcn_mfma_f32_16x16x32_bf16(qf[1][1], k1, accp[1], 0, 0, 0);
    }
    bf16x8 kreg0 = ld8u(kb + (size_t)(64 + wm * 16 + li) * D_ + quad * 8);
    bf16x8 kreg1 = ld8u(kb + (size_t)(64 + wm * 16 + li) * D_ + 32 + quad * 8);

    for (int t = 0; t < 32; ++t) {
        const int cur = t & 1;
        // (a) issue V(t+1) stage into the other buffer (async, not waited here)
        if (t < 31) {
            #pragma unroll
            for (int it = 0; it < 4; ++it) {
                int rbase = wave * 32 + it * 8;
                gload16(vb + (size_t)(rbase + lrow8) * N_ + (t + 1) * 64 + lseg * 8,
                        &Vl[cur ^ 1][rbase * 64]);
            }
        }
        // (b) P-write(t): exp(accp) -> swizzled LDS; accumulate row sums
        #pragma unroll
        for (int i = 0; i < 2; ++i)
            #pragma unroll
            for (int j = 0; j < 4; ++j) {
                int r = wq * 32 + i * 16 + quad * 4 + j;
                int m = wm * 16 + li;
                float e = __expf(fminf(accp[i][j], 60.f));
                s4[i][j] += e;
                *(__bf16*)&Pl[r * 64 + (((m >> 3) ^ (r & 7)) * 8) + (m & 7)] = (__bf16)e;
            }
        // (c) QK(t+1) from kreg; (d) prefetch kreg(t+2)
        if (t < 31) {
            f32x4 np0 = (f32x4){0.f, 0.f, 0.f, 0.f};
            f32x4 np1 = (f32x4){0.f, 0.f, 0.f, 0.f};
            np0 = __builtin_amdgcn_mfma_f32_16x16x32_bf16(qf[0][0], kreg0, np0, 0, 0, 0);
            np1 = __builtin_amdgcn_mfma_f32_16x16x32_bf16(qf[1][0], kreg0, np1, 0, 0, 0);
            np0 = __builtin_amdgcn_mfma_f32_16x16x32_bf16(qf[0][1], kreg1, np0, 0, 0, 0);
            np1 = __builtin_amdgcn_mfma_f32_16x16x32_bf16(qf[1][1], kreg1, np1, 0, 0, 0);
            if (t < 30) {
                kreg0 = ld8u(kb + (size_t)((t + 2) * 64 + wm * 16 + li) * D_ + quad * 8);
                kreg1 = ld8u(kb + (size_t)((t + 2) * 64 + wm * 16 + li) * D_ + 32 + quad * 8);
            }
            accp[0] = np0;
            accp[1] = np1;
        }
        // barrier 1: counted vmcnt leaves next-tile loads in flight
        if (t < 30)       asm volatile("s_waitcnt vmcnt(6) lgkmcnt(0)" ::: "memory");
        else if (t == 30) asm volatile("s_waitcnt vmcnt(4) lgkmcnt(0)" ::: "memory");
        else              asm volatile("s_waitcnt vmcnt(0) lgkmcnt(0)" ::: "memory");
        __builtin_amdgcn_sched_barrier(0);
        __builtin_amdgcn_s_barrier();
        __builtin_amdgcn_sched_barrier(0);

        // PV(t): A = P rows (wq half), B = V rows c (wm range)
        __builtin_amdgcn_s_setprio(1);
        #pragma unroll
        for (int ks = 0; ks < 2; ++ks) {
            bf16x8 af[2];
            #pragma unroll
            for (int i = 0; i < 2; ++i)
                af[i] = *(const bf16x8*)&Pl[(wq * 32 + i * 16 + li) * 64
                                            + (((ks * 4 + quad) ^ (li & 7)) * 8)];
            #pragma unroll
            for (int j = 0; j < 4; ++j) {
                bf16x8 vf = *(const bf16x8*)&Vl[cur][(wm * 64 + j * 16 + li) * 64
                                                    + (((ks * 4 + quad) ^ (li & 7)) * 8)];
                #pragma unroll
                for (int i = 0; i < 2; ++i)
                    acc[i][j] = __builtin_amdgcn_mfma_f32_16x16x32_bf16(
                        af[i], vf, acc[i][j], 0, 0, 0);
            }
        }
        __builtin_amdgcn_s_setprio(0);

        // barrier 2: Pl / Vl[cur] reads done block-wide before next overwrite
        __builtin_amdgcn_sched_barrier(0);
        __builtin_amdgcn_s_barrier();
        __builtin_amdgcn_sched_barrier(0);
    }

    // l reduction: shfl over the 16 li lanes, then add the 4 wm-partner waves
    __syncthreads();
    if (tid < 64) ll[tid] = 0.f;
    __syncthreads();
    #pragma unroll
    for (int i = 0; i < 2; ++i)
        #pragma unroll
        for (int j = 0; j < 4; ++j) {
            float s = s4[i][j];
            s += __shfl_xor(s, 1, 64);
            s += __shfl_xor(s, 2, 64);
            s += __shfl_xor(s, 4, 64);
            s += __shfl_xor(s, 8, 64);
            if (li == 0) atomicAdd(&ll[wq * 32 + i * 16 + quad * 4 + j], s);
        }
    __syncthreads();

    const int isf32 = *flag;
    const float g = isf32 ? ((const float*)gptr)[0] : bf2f(((const ushort*)gptr)[0]);
    const ushort* xu = (const ushort*)x;
    const float*  xf = (const float*)x;
    ushort* ou = (ushort*)out;
    float*  of = (float*)out;
    #pragma unroll
    for (int i = 0; i < 2; ++i)
        #pragma unroll
        for (int jj = 0; jj < 4; ++jj) {
            int nl = wq * 32 + i * 16 + quad * 4 + jj;
            float inv = 1.f / ll[nl];
            size_t rowb = ((size_t)(b * N_ + q0 + nl)) * C_;
            #pragma unroll
            for (int j = 0; j < 4; ++j) {
                int cg = c0 + wm * 64 + j * 16 + li;
                size_t idx = rowb + cg;
                float xv  = isf32 ? xf[idx] : bf2f(xu[idx]);
                float val = g * (acc[i][j][jj] * inv) + xv;
                if (isf32) of[idx] = val; else ou[idx] = f2bf(val);
            }
        }
}

extern "C" void kernel_launch(void* const* d_in, const int* in_sizes, int n_in,
                              void* d_out, int out_size, void* d_ws, size_t ws_size,
                              hipStream_t stream) {
    (void)in_sizes; (void)n_in; (void)out_size; (void)ws_size;
    const void* x     = d_in[0];
    const void* Wq    = d_in[1];
    const void* bq    = d_in[2];
    const void* Wk    = d_in[3];
    const void* bk    = d_in[4];
    const void* Wv    = d_in[5];
    const void* bv    = d_in[6];
    const void* gamma = d_in[7];

    // workspace: flag(256B) + q(4M) + k(4M) + vt(32M, all batches) = ~40 MB
    int*    flag = (int*)d_ws;
    ushort* q    = (ushort*)((char*)d_ws + 256);
    ushort* kk   = q  + (size_t)B_ * N_ * D_;   // [B, N, 64] bf16
    ushort* vt   = kk + (size_t)B_ * N_ * D_;   // [B, C, N] bf16

    probe_kernel<<<1, 64, 0, stream>>>(x, flag);

    const int M = B_ * N_;  // 32768
    proj_qk_kernel<<<dim3(M / 64), 256, 0, stream>>>(x, Wq, bq, Wk, bk, q, kk, flag);
    proj_kernel<C_, 1><<<dim3(M / 64, C_ / 64), 256, 0, stream>>>(
        x, Wv, bv, vt, flag, 0);
    attn_fused<<<dim3(N_ / 64, 2, B_), 512, 0, stream>>>(
        q, kk, vt, x, gamma, d_out, flag);
}

// Round 11
// 303.849 us; speedup vs baseline: 1.4734x; 1.0865x over previous
//
#include <hip/hip_runtime.h>
#include <hip/hip_bf16.h>

typedef __bf16 bf16x8 __attribute__((ext_vector_type(8)));
typedef float f32x4 __attribute__((ext_vector_type(4)));

#define B_ 16
#define N_ 2048
#define C_ 512
#define D_ 64

__device__ __forceinline__ float bf2f(ushort u) {
    union { uint i; float f; } w; w.i = ((uint)u) << 16; return w.f;
}
__device__ __forceinline__ ushort f2bf(float f) {
    union { float f; uint i; } w; w.f = f;
    uint u = w.i;
    u = (u + 0x7fffu + ((u >> 16) & 1u)) >> 16;
    return (ushort)u;
}
__device__ __forceinline__ __bf16 u2b(ushort u) {
    union { ushort s; __bf16 b; } w; w.s = u; return w.b;
}
__device__ __forceinline__ bf16x8 ld8u(const ushort* p) { return *(const bf16x8*)p; }
__device__ __forceinline__ bf16x8 ld8f(const float* p) {
    f32x4 a = *(const f32x4*)p;
    f32x4 b = *(const f32x4*)(p + 4);
    bf16x8 r;
    r[0] = u2b(f2bf(a[0])); r[1] = u2b(f2bf(a[1]));
    r[2] = u2b(f2bf(a[2])); r[3] = u2b(f2bf(a[3]));
    r[4] = u2b(f2bf(b[0])); r[5] = u2b(f2bf(b[1]));
    r[6] = u2b(f2bf(b[2])); r[7] = u2b(f2bf(b[3]));
    return r;
}

// async global->LDS, 16 B per lane; LDS dest = wave-uniform base + lane*16
__device__ __forceinline__ void gload16(const ushort* g, ushort* l) {
    __builtin_amdgcn_global_load_lds(
        (const __attribute__((address_space(1))) void*)g,
        (__attribute__((address_space(3))) void*)l, 16, 0, 0);
}

// Decide whether float tensors are stored as f32 or bf16 (bench: f32).
__global__ void probe_kernel(const void* x, int* flag) {
    int lane = threadIdx.x & 63;
    ushort u = ((const ushort*)x)[lane * 2];
    float v = fabsf(bf2f(u));
    bool sane = (v > 9.3e-10f) && (v < 1.1e9f) && (v == v);
    unsigned long long m = __ballot(sane);
    if (threadIdx.x == 0) *flag = (__popcll(m) >= 48) ? 0 : 1;  // 0=bf16, 1=f32
}

// Merged Q+K+V projection as ONE 128x128-tile B^T GEMM:
//   out[m, n] = sum_k X[m,k] * W_all[n,k] + b_all[n],  n in [0,640)
//   n <  64 : Wq/bq -> q  [M][64]
//   n < 128 : Wk/bk -> kk [M][64]
//   else    : Wv/bv -> vt [b][c][ml] (transposed per batch, ushort4 pack)
// 128x128 tile, 4 waves, reg-staged f32->bf16 into [128][72]-padded LDS
// (same fragment layout as the 64-tile proj kernels; 4x acc per staged byte).
__launch_bounds__(256, 2)
__global__ void proj_all(const void* __restrict__ X,
                         const void* __restrict__ Wq_, const void* __restrict__ bq_,
                         const void* __restrict__ Wk_, const void* __restrict__ bk_,
                         const void* __restrict__ Wv_, const void* __restrict__ bv_,
                         ushort* __restrict__ outq,
                         ushort* __restrict__ outk,
                         ushort* __restrict__ outv,
                         const int* __restrict__ flag) {
    const int isf32 = *flag;
    __shared__ ushort lA[128][72];
    __shared__ ushort lB[128][72];
    const int tid  = threadIdx.x;
    const int wave = tid >> 6, lane = tid & 63;
    const int quad = lane >> 4, li = lane & 15;
    const int wr = (wave & 1) * 64;
    const int wc = (wave >> 1) * 64;
    const int m0 = blockIdx.x * 128;
    const int n0 = blockIdx.y * 128;

    f32x4 acc[4][4];
    #pragma unroll
    for (int i = 0; i < 4; ++i)
        #pragma unroll
        for (int j = 0; j < 4; ++j) acc[i][j] = (f32x4){0.f, 0.f, 0.f, 0.f};

    for (int k0 = 0; k0 < C_; k0 += 64) {
        __syncthreads();
        #pragma unroll
        for (int it = 0; it < 4; ++it) {
            int idx = tid + it * 256;
            int row = idx >> 3, seg = idx & 7;
            int n = n0 + row;
            size_t ea = (size_t)(m0 + row) * C_ + k0 + seg * 8;
            if (!isf32) {
                const ushort* bs = (n < 64)  ? (const ushort*)Wq_ + (size_t)n * C_
                                 : (n < 128) ? (const ushort*)Wk_ + (size_t)(n - 64) * C_
                                             : (const ushort*)Wv_ + (size_t)(n - 128) * C_;
                *(bf16x8*)&lA[row][seg * 8] = ld8u((const ushort*)X + ea);
                *(bf16x8*)&lB[row][seg * 8] = ld8u(bs + k0 + seg * 8);
            } else {
                const float* bs = (n < 64)  ? (const float*)Wq_ + (size_t)n * C_
                                : (n < 128) ? (const float*)Wk_ + (size_t)(n - 64) * C_
                                            : (const float*)Wv_ + (size_t)(n - 128) * C_;
                *(bf16x8*)&lA[row][seg * 8] = ld8f((const float*)X + ea);
                *(bf16x8*)&lB[row][seg * 8] = ld8f(bs + k0 + seg * 8);
            }
        }
        __syncthreads();
        #pragma unroll
        for (int ks = 0; ks < 2; ++ks) {
            bf16x8 af[4], bfr[4];
            #pragma unroll
            for (int i = 0; i < 4; ++i)
                af[i] = *(const bf16x8*)&lA[wr + i * 16 + li][ks * 32 + quad * 8];
            #pragma unroll
            for (int j = 0; j < 4; ++j)
                bfr[j] = *(const bf16x8*)&lB[wc + j * 16 + li][ks * 32 + quad * 8];
            #pragma unroll
            for (int i = 0; i < 4; ++i)
                #pragma unroll
                for (int j = 0; j < 4; ++j)
                    acc[i][j] = __builtin_amdgcn_mfma_f32_16x16x32_bf16(
                        af[i], bfr[j], acc[i][j], 0, 0, 0);
        }
    }

    #pragma unroll
    for (int j2 = 0; j2 < 4; ++j2) {
        int c = n0 + wc + j2 * 16 + li;
        float bv;
        if (!isf32) {
            bv = (c < 64)  ? bf2f(((const ushort*)bq_)[c])
               : (c < 128) ? bf2f(((const ushort*)bk_)[c - 64])
                           : bf2f(((const ushort*)bv_)[c - 128]);
        } else {
            bv = (c < 64)  ? ((const float*)bq_)[c]
               : (c < 128) ? ((const float*)bk_)[c - 64]
                           : ((const float*)bv_)[c - 128];
        }
        if (c < 128) {
            ushort* dst = (c < 64) ? outq : outk;
            int cl = c & 63;
            #pragma unroll
            for (int i = 0; i < 4; ++i)
                #pragma unroll
                for (int j = 0; j < 4; ++j) {
                    int m = m0 + wr + i * 16 + quad * 4 + j;
                    dst[(size_t)m * D_ + cl] = f2bf(acc[i][j2][j] + bv);
                }
        } else {
            int cv = c - 128;
            #pragma unroll
            for (int i = 0; i < 4; ++i) {
                int m = m0 + wr + i * 16 + quad * 4;
                int b = m >> 11, ml = m & (N_ - 1);
                ushort4 pk;
                pk.x = f2bf(acc[i][j2][0] + bv);
                pk.y = f2bf(acc[i][j2][1] + bv);
                pk.z = f2bf(acc[i][j2][2] + bv);
                pk.w = f2bf(acc[i][j2][3] + bv);
                *(ushort4*)(outv + ((size_t)(b * C_ + cv)) * N_ + ml) = pk;
            }
        }
    }
}

// Fused attention v3: double-buffered V with counted-vmcnt raw barriers
// (T3/T4-lite) + K register prefetch + setprio around PV (T5).
// (unchanged from round 10 — measured 150.8 us, MfmaUtil 24%, Occ 41%)
__launch_bounds__(512, 4)
__global__ void attn_fused(const ushort* __restrict__ q,
                           const ushort* __restrict__ kk,
                           const ushort* __restrict__ vt,
                           const void* __restrict__ x,
                           const void* __restrict__ gptr,
                           void* __restrict__ out,
                           const int* __restrict__ flag) {
    __shared__ ushort Vl[2][256 * 64];   // 2 x 32 KB V tile (swizzled, rows=c)
    __shared__ ushort Pl[64 * 64];       //  8 KB P tile (swizzled)
    __shared__ float  ll[64];            // row sums

    const int tid  = threadIdx.x;
    const int wave = tid >> 6, lane = tid & 63;
    const int quad = lane >> 4, li = lane & 15;
    const int wq = wave & 1;          // q-half (32 rows)
    const int wm = wave >> 1;         // 16-wide m-range (QK) / 64-wide c-range (PV)
    const int b  = blockIdx.z;
    const int q0 = blockIdx.x * 64;
    const int c0 = blockIdx.y * 256;

    const ushort* kb = kk + (size_t)b * N_ * D_;
    const ushort* vb = vt + ((size_t)b * C_ + c0) * N_;

    // staging lane constants (pre-swizzled global source -> linear LDS dest)
    const int lrow8 = lane >> 3;               // 0..7
    const int lseg  = (lane & 7) ^ lrow8;      // XOR'd 16B granule

    // Q fragments: rows q0 + wq*32 + i*16 + li
    bf16x8 qf[2][2];
    #pragma unroll
    for (int i = 0; i < 2; ++i)
        #pragma unroll
        for (int ks = 0; ks < 2; ++ks)
            qf[i][ks] = ld8u(q + ((size_t)(b * N_ + q0 + wq * 32 + i * 16 + li)) * D_
                               + ks * 32 + quad * 8);

    f32x4 acc[2][4];   // O rows wq*32+i*16+quad*4+jj, cols c0+wm*64+j*16+li
    #pragma unroll
    for (int i = 0; i < 2; ++i)
        #pragma unroll
        for (int j = 0; j < 4; ++j) acc[i][j] = (f32x4){0.f, 0.f, 0.f, 0.f};

    f32x4 accp[2];     // P rows wq*32+i*16+quad*4+j, m col wm*16+li
    float s4[2][4];
    #pragma unroll
    for (int i = 0; i < 2; ++i) {
        accp[i] = (f32x4){0.f, 0.f, 0.f, 0.f};
        #pragma unroll
        for (int j = 0; j < 4; ++j) s4[i][j] = 0.f;
    }

    // prologue: stage V(0) -> Vl[0]; QK(0) with direct K loads; kreg = K(1)
    #pragma unroll
    for (int it = 0; it < 4; ++it) {
        int rbase = wave * 32 + it * 8;
        gload16(vb + (size_t)(rbase + lrow8) * N_ + lseg * 8, &Vl[0][rbase * 64]);
    }
    {
        bf16x8 k0 = ld8u(kb + (size_t)(wm * 16 + li) * D_ + quad * 8);
        bf16x8 k1 = ld8u(kb + (size_t)(wm * 16 + li) * D_ + 32 + quad * 8);
        accp[0] = __builtin_amdgcn_mfma_f32_16x16x32_bf16(qf[0][0], k0, accp[0], 0, 0, 0);
        accp[1] = __builtin_amdgcn_mfma_f32_16x16x32_bf16(qf[1][0], k0, accp[1], 0, 0, 0);
        accp[0] = __builtin_amdgcn_mfma_f32_16x16x32_bf16(qf[0][1], k1, accp[0], 0, 0, 0);
        accp[1] = __builtin_amdgcn_mfma_f32_16x16x32_bf16(qf[1][1], k1, accp[1], 0, 0, 0);
    }
    bf16x8 kreg0 = ld8u(kb + (size_t)(64 + wm * 16 + li) * D_ + quad * 8);
    bf16x8 kreg1 = ld8u(kb + (size_t)(64 + wm * 16 + li) * D_ + 32 + quad * 8);

    for (int t = 0; t < 32; ++t) {
        const int cur = t & 1;
        // (a) issue V(t+1) stage into the other buffer (async, not waited here)
        if (t < 31) {
            #pragma unroll
            for (int it = 0; it < 4; ++it) {
                int rbase = wave * 32 + it * 8;
                gload16(vb + (size_t)(rbase + lrow8) * N_ + (t + 1) * 64 + lseg * 8,
                        &Vl[cur ^ 1][rbase * 64]);
            }
        }
        // (b) P-write(t): exp(accp) -> swizzled LDS; accumulate row sums
        #pragma unroll
        for (int i = 0; i < 2; ++i)
            #pragma unroll
            for (int j = 0; j < 4; ++j) {
                int r = wq * 32 + i * 16 + quad * 4 + j;
                int m = wm * 16 + li;
                float e = __expf(fminf(accp[i][j], 60.f));
                s4[i][j] += e;
                *(__bf16*)&Pl[r * 64 + (((m >> 3) ^ (r & 7)) * 8) + (m & 7)] = (__bf16)e;
            }
        // (c) QK(t+1) from kreg; (d) prefetch kreg(t+2)
        if (t < 31) {
            f32x4 np0 = (f32x4){0.f, 0.f, 0.f, 0.f};
            f32x4 np1 = (f32x4){0.f, 0.f, 0.f, 0.f};
            np0 = __builtin_amdgcn_mfma_f32_16x16x32_bf16(qf[0][0], kreg0, np0, 0, 0, 0);
            np1 = __builtin_amdgcn_mfma_f32_16x16x32_bf16(qf[1][0], kreg0, np1, 0, 0, 0);
            np0 = __builtin_amdgcn_mfma_f32_16x16x32_bf16(qf[0][1], kreg1, np0, 0, 0, 0);
            np1 = __builtin_amdgcn_mfma_f32_16x16x32_bf16(qf[1][1], kreg1, np1, 0, 0, 0);
            if (t < 30) {
                kreg0 = ld8u(kb + (size_t)((t + 2) * 64 + wm * 16 + li) * D_ + quad * 8);
                kreg1 = ld8u(kb + (size_t)((t + 2) * 64 + wm * 16 + li) * D_ + 32 + quad * 8);
            }
            accp[0] = np0;
            accp[1] = np1;
        }
        // barrier 1: counted vmcnt leaves next-tile loads in flight
        if (t < 30)       asm volatile("s_waitcnt vmcnt(6) lgkmcnt(0)" ::: "memory");
        else if (t == 30) asm volatile("s_waitcnt vmcnt(4) lgkmcnt(0)" ::: "memory");
        else              asm volatile("s_waitcnt vmcnt(0) lgkmcnt(0)" ::: "memory");
        __builtin_amdgcn_sched_barrier(0);
        __builtin_amdgcn_s_barrier();
        __builtin_amdgcn_sched_barrier(0);

        // PV(t): A = P rows (wq half), B = V rows c (wm range)
        __builtin_amdgcn_s_setprio(1);
        #pragma unroll
        for (int ks = 0; ks < 2; ++ks) {
            bf16x8 af[2];
            #pragma unroll
            for (int i = 0; i < 2; ++i)
                af[i] = *(const bf16x8*)&Pl[(wq * 32 + i * 16 + li) * 64
                                            + (((ks * 4 + quad) ^ (li & 7)) * 8)];
            #pragma unroll
            for (int j = 0; j < 4; ++j) {
                bf16x8 vf = *(const bf16x8*)&Vl[cur][(wm * 64 + j * 16 + li) * 64
                                                    + (((ks * 4 + quad) ^ (li & 7)) * 8)];
                #pragma unroll
                for (int i = 0; i < 2; ++i)
                    acc[i][j] = __builtin_amdgcn_mfma_f32_16x16x32_bf16(
                        af[i], vf, acc[i][j], 0, 0, 0);
            }
        }
        __builtin_amdgcn_s_setprio(0);

        // barrier 2: Pl / Vl[cur] reads done block-wide before next overwrite
        __builtin_amdgcn_sched_barrier(0);
        __builtin_amdgcn_s_barrier();
        __builtin_amdgcn_sched_barrier(0);
    }

    // l reduction: shfl over the 16 li lanes, then add the 4 wm-partner waves
    __syncthreads();
    if (tid < 64) ll[tid] = 0.f;
    __syncthreads();
    #pragma unroll
    for (int i = 0; i < 2; ++i)
        #pragma unroll
        for (int j = 0; j < 4; ++j) {
            float s = s4[i][j];
            s += __shfl_xor(s, 1, 64);
            s += __shfl_xor(s, 2, 64);
            s += __shfl_xor(s, 4, 64);
            s += __shfl_xor(s, 8, 64);
            if (li == 0) atomicAdd(&ll[wq * 32 + i * 16 + quad * 4 + j], s);
        }
    __syncthreads();

    const int isf32 = *flag;
    const float g = isf32 ? ((const float*)gptr)[0] : bf2f(((const ushort*)gptr)[0]);
    const ushort* xu = (const ushort*)x;
    const float*  xf = (const float*)x;
    ushort* ou = (ushort*)out;
    float*  of = (float*)out;
    #pragma unroll
    for (int i = 0; i < 2; ++i)
        #pragma unroll
        for (int jj = 0; jj < 4; ++jj) {
            int nl = wq * 32 + i * 16 + quad * 4 + jj;
            float inv = 1.f / ll[nl];
            size_t rowb = ((size_t)(b * N_ + q0 + nl)) * C_;
            #pragma unroll
            for (int j = 0; j < 4; ++j) {
                int cg = c0 + wm * 64 + j * 16 + li;
                size_t idx = rowb + cg;
                float xv  = isf32 ? xf[idx] : bf2f(xu[idx]);
                float val = g * (acc[i][j][jj] * inv) + xv;
                if (isf32) of[idx] = val; else ou[idx] = f2bf(val);
            }
        }
}

extern "C" void kernel_launch(void* const* d_in, const int* in_sizes, int n_in,
                              void* d_out, int out_size, void* d_ws, size_t ws_size,
                              hipStream_t stream) {
    (void)in_sizes; (void)n_in; (void)out_size; (void)ws_size;
    const void* x     = d_in[0];
    const void* Wq    = d_in[1];
    const void* bq    = d_in[2];
    const void* Wk    = d_in[3];
    const void* bk    = d_in[4];
    const void* Wv    = d_in[5];
    const void* bv    = d_in[6];
    const void* gamma = d_in[7];

    // workspace: flag(256B) + q(4M) + k(4M) + vt(32M, all batches) = ~40 MB
    int*    flag = (int*)d_ws;
    ushort* q    = (ushort*)((char*)d_ws + 256);
    ushort* kk   = q  + (size_t)B_ * N_ * D_;   // [B, N, 64] bf16
    ushort* vt   = kk + (size_t)B_ * N_ * D_;   // [B, C, N] bf16

    probe_kernel<<<1, 64, 0, stream>>>(x, flag);

    // one merged projection GEMM: M=32768, N=640 (64 q | 64 k | 512 v), K=512
    proj_all<<<dim3(B_ * N_ / 128, 640 / 128), 256, 0, stream>>>(
        x, Wq, bq, Wk, bk, Wv, bv, q, kk, vt, flag);

    attn_fused<<<dim3(N_ / 64, 2, B_), 512, 0, stream>>>(
        q, kk, vt, x, gamma, d_out, flag);
}

// Round 12
// 292.531 us; speedup vs baseline: 1.5304x; 1.0387x over previous
//
#include <hip/hip_runtime.h>
#include <hip/hip_bf16.h>

typedef __bf16 bf16x8 __attribute__((ext_vector_type(8)));
typedef float f32x4 __attribute__((ext_vector_type(4)));

#define B_ 16
#define N_ 2048
#define C_ 512
#define D_ 64

__device__ __forceinline__ float bf2f(ushort u) {
    union { uint i; float f; } w; w.i = ((uint)u) << 16; return w.f;
}
__device__ __forceinline__ ushort f2bf(float f) {
    union { float f; uint i; } w; w.f = f;
    uint u = w.i;
    u = (u + 0x7fffu + ((u >> 16) & 1u)) >> 16;
    return (ushort)u;
}
__device__ __forceinline__ __bf16 u2b(ushort u) {
    union { ushort s; __bf16 b; } w; w.s = u; return w.b;
}
__device__ __forceinline__ bf16x8 ld8u(const ushort* p) { return *(const bf16x8*)p; }
__device__ __forceinline__ bf16x8 ld8f(const float* p) {
    f32x4 a = *(const f32x4*)p;
    f32x4 b = *(const f32x4*)(p + 4);
    bf16x8 r;
    r[0] = u2b(f2bf(a[0])); r[1] = u2b(f2bf(a[1]));
    r[2] = u2b(f2bf(a[2])); r[3] = u2b(f2bf(a[3]));
    r[4] = u2b(f2bf(b[0])); r[5] = u2b(f2bf(b[1]));
    r[6] = u2b(f2bf(b[2])); r[7] = u2b(f2bf(b[3]));
    return r;
}

// async global->LDS, 16 B per lane; LDS dest = wave-uniform base + lane*16
__device__ __forceinline__ void gload16(const ushort* g, ushort* l) {
    __builtin_amdgcn_global_load_lds(
        (const __attribute__((address_space(1))) void*)g,
        (__attribute__((address_space(3))) void*)l, 16, 0, 0);
}

// Decide whether float tensors are stored as f32 or bf16 (bench: f32).
__global__ void probe_kernel(const void* x, int* flag) {
    int lane = threadIdx.x & 63;
    ushort u = ((const ushort*)x)[lane * 2];
    float v = fabsf(bf2f(u));
    bool sane = (v > 9.3e-10f) && (v < 1.1e9f) && (v == v);
    unsigned long long m = __ballot(sane);
    if (threadIdx.x == 0) *flag = (__popcll(m) >= 48) ? 0 : 1;  // 0=bf16, 1=f32
}

// One memory-bound pass: X -> xbf (bf16), pack [Wq|Wk|Wv] -> wall (bf16).
// Moves the f32->bf16 conversion OFF the GEMM staging critical path.
__global__ void convert_kernel(const void* __restrict__ X,
                               const void* __restrict__ Wq_,
                               const void* __restrict__ Wk_,
                               const void* __restrict__ Wv_,
                               ushort* __restrict__ xbf,
                               ushort* __restrict__ wall,
                               const int* __restrict__ flag) {
    const int isf32 = *flag;
    const size_t NX  = (size_t)B_ * N_ * C_;   // 16,777,216
    const size_t NWQ = (size_t)D_ * C_;        // 32,768
    const size_t NWV = (size_t)C_ * C_;        // 262,144
    const size_t total8 = (NX + 2 * NWQ + NWV) / 8;
    const size_t stride = (size_t)gridDim.x * blockDim.x;
    for (size_t v = (size_t)blockIdx.x * blockDim.x + threadIdx.x; v < total8; v += stride) {
        size_t e = v * 8;
        const void* src;
        size_t off;
        ushort* dst;
        if (e < NX)                { src = X;   off = e;                dst = xbf + e; }
        else if (e < NX + NWQ)     { src = Wq_; off = e - NX;           dst = wall + (e - NX); }
        else if (e < NX + 2 * NWQ) { src = Wk_; off = e - NX - NWQ;     dst = wall + (e - NX); }
        else                       { src = Wv_; off = e - NX - 2 * NWQ; dst = wall + (e - NX); }
        bf16x8 r = isf32 ? ld8f((const float*)src + off) : ld8u((const ushort*)src + off);
        *(bf16x8*)dst = r;
    }
}

// Merged Q+K+V projection, bf16-in, m97 structure (global_load_lds + XOR
// swizzle — the harness-verified gemm128 staging/fragment layout):
//   out[m, n] = sum_k xbf[m,k] * wall[n,k] + b_all[n],  n in [0,640)
//   n <  64 : -> q  [M][64]     (+bq, f32 from original ptr)
//   n < 128 : -> kk [M][64]     (+bk)
//   else    : -> vt [b][c][ml]  (+bv, transposed per batch, ushort4 pack)
__launch_bounds__(256, 2)
__global__ void proj_all(const ushort* __restrict__ xbf,
                         const ushort* __restrict__ wall,
                         const void* __restrict__ bq_,
                         const void* __restrict__ bk_,
                         const void* __restrict__ bv_,
                         ushort* __restrict__ outq,
                         ushort* __restrict__ outk,
                         ushort* __restrict__ outv,
                         const int* __restrict__ flag) {
    __shared__ ushort lA[128 * 64];
    __shared__ ushort lB[128 * 64];
    const int tid  = threadIdx.x;
    const int wave = tid >> 6, lane = tid & 63;
    const int quad = lane >> 4, li = lane & 15;
    const int wr = (wave & 1) * 64;
    const int wc = (wave >> 1) * 64;
    const int n0 = blockIdx.x * 128;   // 5 n-tiles (fastest -> A-panel L2 reuse)
    const int m0 = blockIdx.y * 128;

    const int lrow8 = lane >> 3;
    const int lseg  = (lane & 7) ^ (lrow8 & 7);

    f32x4 acc[4][4];
    #pragma unroll
    for (int i = 0; i < 4; ++i)
        #pragma unroll
        for (int j = 0; j < 4; ++j) acc[i][j] = (f32x4){0.f, 0.f, 0.f, 0.f};

    for (int k0 = 0; k0 < C_; k0 += 64) {
        __syncthreads();
        #pragma unroll
        for (int i = 0; i < 4; ++i) {
            int rbase = wave * 32 + i * 8;
            gload16(xbf  + (size_t)(m0 + rbase + lrow8) * C_ + k0 + lseg * 8,
                    &lA[rbase * 64]);
            gload16(wall + (size_t)(n0 + rbase + lrow8) * C_ + k0 + lseg * 8,
                    &lB[rbase * 64]);
        }
        __syncthreads();
        #pragma unroll
        for (int ks = 0; ks < 2; ++ks) {
            bf16x8 af[4], bfr[4];
            #pragma unroll
            for (int i = 0; i < 4; ++i) {
                int row = wr + i * 16 + li;
                af[i] = *(const bf16x8*)&lA[row * 64 + (((ks * 4 + quad) ^ (li & 7)) * 8)];
            }
            #pragma unroll
            for (int j = 0; j < 4; ++j) {
                int row = wc + j * 16 + li;
                bfr[j] = *(const bf16x8*)&lB[row * 64 + (((ks * 4 + quad) ^ (li & 7)) * 8)];
            }
            #pragma unroll
            for (int i = 0; i < 4; ++i)
                #pragma unroll
                for (int j = 0; j < 4; ++j)
                    acc[i][j] = __builtin_amdgcn_mfma_f32_16x16x32_bf16(
                        af[i], bfr[j], acc[i][j], 0, 0, 0);
        }
    }

    const int isf32 = *flag;
    #pragma unroll
    for (int j2 = 0; j2 < 4; ++j2) {
        int c = n0 + wc + j2 * 16 + li;
        float bv;
        if (!isf32) {
            bv = (c < 64)  ? bf2f(((const ushort*)bq_)[c])
               : (c < 128) ? bf2f(((const ushort*)bk_)[c - 64])
                           : bf2f(((const ushort*)bv_)[c - 128]);
        } else {
            bv = (c < 64)  ? ((const float*)bq_)[c]
               : (c < 128) ? ((const float*)bk_)[c - 64]
                           : ((const float*)bv_)[c - 128];
        }
        if (c < 128) {
            ushort* dst = (c < 64) ? outq : outk;
            int cl = c & 63;
            #pragma unroll
            for (int i = 0; i < 4; ++i)
                #pragma unroll
                for (int j = 0; j < 4; ++j) {
                    int m = m0 + wr + i * 16 + quad * 4 + j;
                    dst[(size_t)m * D_ + cl] = f2bf(acc[i][j2][j] + bv);
                }
        } else {
            int cv = c - 128;
            #pragma unroll
            for (int i = 0; i < 4; ++i) {
                int m = m0 + wr + i * 16 + quad * 4;
                int b = m >> 11, ml = m & (N_ - 1);
                ushort4 pk;
                pk.x = f2bf(acc[i][j2][0] + bv);
                pk.y = f2bf(acc[i][j2][1] + bv);
                pk.z = f2bf(acc[i][j2][2] + bv);
                pk.w = f2bf(acc[i][j2][3] + bv);
                *(ushort4*)(outv + ((size_t)(b * C_ + cv)) * N_ + ml) = pk;
            }
        }
    }
}

// Fused attention v3: double-buffered V with counted-vmcnt raw barriers
// (T3/T4-lite) + K register prefetch + setprio around PV (T5).
// (unchanged — measured 152 us, MfmaUtil 24%, Occ 41%, structural plateau)
__launch_bounds__(512, 4)
__global__ void attn_fused(const ushort* __restrict__ q,
                           const ushort* __restrict__ kk,
                           const ushort* __restrict__ vt,
                           const void* __restrict__ x,
                           const void* __restrict__ gptr,
                           void* __restrict__ out,
                           const int* __restrict__ flag) {
    __shared__ ushort Vl[2][256 * 64];   // 2 x 32 KB V tile (swizzled, rows=c)
    __shared__ ushort Pl[64 * 64];       //  8 KB P tile (swizzled)
    __shared__ float  ll[64];            // row sums

    const int tid  = threadIdx.x;
    const int wave = tid >> 6, lane = tid & 63;
    const int quad = lane >> 4, li = lane & 15;
    const int wq = wave & 1;          // q-half (32 rows)
    const int wm = wave >> 1;         // 16-wide m-range (QK) / 64-wide c-range (PV)
    const int b  = blockIdx.z;
    const int q0 = blockIdx.x * 64;
    const int c0 = blockIdx.y * 256;

    const ushort* kb = kk + (size_t)b * N_ * D_;
    const ushort* vb = vt + ((size_t)b * C_ + c0) * N_;

    // staging lane constants (pre-swizzled global source -> linear LDS dest)
    const int lrow8 = lane >> 3;               // 0..7
    const int lseg  = (lane & 7) ^ lrow8;      // XOR'd 16B granule

    // Q fragments: rows q0 + wq*32 + i*16 + li
    bf16x8 qf[2][2];
    #pragma unroll
    for (int i = 0; i < 2; ++i)
        #pragma unroll
        for (int ks = 0; ks < 2; ++ks)
            qf[i][ks] = ld8u(q + ((size_t)(b * N_ + q0 + wq * 32 + i * 16 + li)) * D_
                               + ks * 32 + quad * 8);

    f32x4 acc[2][4];   // O rows wq*32+i*16+quad*4+jj, cols c0+wm*64+j*16+li
    #pragma unroll
    for (int i = 0; i < 2; ++i)
        #pragma unroll
        for (int j = 0; j < 4; ++j) acc[i][j] = (f32x4){0.f, 0.f, 0.f, 0.f};

    f32x4 accp[2];     // P rows wq*32+i*16+quad*4+j, m col wm*16+li
    float s4[2][4];
    #pragma unroll
    for (int i = 0; i < 2; ++i) {
        accp[i] = (f32x4){0.f, 0.f, 0.f, 0.f};
        #pragma unroll
        for (int j = 0; j < 4; ++j) s4[i][j] = 0.f;
    }

    // prologue: stage V(0) -> Vl[0]; QK(0) with direct K loads; kreg = K(1)
    #pragma unroll
    for (int it = 0; it < 4; ++it) {
        int rbase = wave * 32 + it * 8;
        gload16(vb + (size_t)(rbase + lrow8) * N_ + lseg * 8, &Vl[0][rbase * 64]);
    }
    {
        bf16x8 k0 = ld8u(kb + (size_t)(wm * 16 + li) * D_ + quad * 8);
        bf16x8 k1 = ld8u(kb + (size_t)(wm * 16 + li) * D_ + 32 + quad * 8);
        accp[0] = __builtin_amdgcn_mfma_f32_16x16x32_bf16(qf[0][0], k0, accp[0], 0, 0, 0);
        accp[1] = __builtin_amdgcn_mfma_f32_16x16x32_bf16(qf[1][0], k0, accp[1], 0, 0, 0);
        accp[0] = __builtin_amdgcn_mfma_f32_16x16x32_bf16(qf[0][1], k1, accp[0], 0, 0, 0);
        accp[1] = __builtin_amdgcn_mfma_f32_16x16x32_bf16(qf[1][1], k1, accp[1], 0, 0, 0);
    }
    bf16x8 kreg0 = ld8u(kb + (size_t)(64 + wm * 16 + li) * D_ + quad * 8);
    bf16x8 kreg1 = ld8u(kb + (size_t)(64 + wm * 16 + li) * D_ + 32 + quad * 8);

    for (int t = 0; t < 32; ++t) {
        const int cur = t & 1;
        // (a) issue V(t+1) stage into the other buffer (async, not waited here)
        if (t < 31) {
            #pragma unroll
            for (int it = 0; it < 4; ++it) {
                int rbase = wave * 32 + it * 8;
                gload16(vb + (size_t)(rbase + lrow8) * N_ + (t + 1) * 64 + lseg * 8,
                        &Vl[cur ^ 1][rbase * 64]);
            }
        }
        // (b) P-write(t): exp(accp) -> swizzled LDS; accumulate row sums
        #pragma unroll
        for (int i = 0; i < 2; ++i)
            #pragma unroll
            for (int j = 0; j < 4; ++j) {
                int r = wq * 32 + i * 16 + quad * 4 + j;
                int m = wm * 16 + li;
                float e = __expf(fminf(accp[i][j], 60.f));
                s4[i][j] += e;
                *(__bf16*)&Pl[r * 64 + (((m >> 3) ^ (r & 7)) * 8) + (m & 7)] = (__bf16)e;
            }
        // (c) QK(t+1) from kreg; (d) prefetch kreg(t+2)
        if (t < 31) {
            f32x4 np0 = (f32x4){0.f, 0.f, 0.f, 0.f};
            f32x4 np1 = (f32x4){0.f, 0.f, 0.f, 0.f};
            np0 = __builtin_amdgcn_mfma_f32_16x16x32_bf16(qf[0][0], kreg0, np0, 0, 0, 0);
            np1 = __builtin_amdgcn_mfma_f32_16x16x32_bf16(qf[1][0], kreg0, np1, 0, 0, 0);
            np0 = __builtin_amdgcn_mfma_f32_16x16x32_bf16(qf[0][1], kreg1, np0, 0, 0, 0);
            np1 = __builtin_amdgcn_mfma_f32_16x16x32_bf16(qf[1][1], kreg1, np1, 0, 0, 0);
            if (t < 30) {
                kreg0 = ld8u(kb + (size_t)((t + 2) * 64 + wm * 16 + li) * D_ + quad * 8);
                kreg1 = ld8u(kb + (size_t)((t + 2) * 64 + wm * 16 + li) * D_ + 32 + quad * 8);
            }
            accp[0] = np0;
            accp[1] = np1;
        }
        // barrier 1: counted vmcnt leaves next-tile loads in flight
        if (t < 30)       asm volatile("s_waitcnt vmcnt(6) lgkmcnt(0)" ::: "memory");
        else if (t == 30) asm volatile("s_waitcnt vmcnt(4) lgkmcnt(0)" ::: "memory");
        else              asm volatile("s_waitcnt vmcnt(0) lgkmcnt(0)" ::: "memory");
        __builtin_amdgcn_sched_barrier(0);
        __builtin_amdgcn_s_barrier();
        __builtin_amdgcn_sched_barrier(0);

        // PV(t): A = P rows (wq half), B = V rows c (wm range)
        __builtin_amdgcn_s_setprio(1);
        #pragma unroll
        for (int ks = 0; ks < 2; ++ks) {
            bf16x8 af[2];
            #pragma unroll
            for (int i = 0; i < 2; ++i)
                af[i] = *(const bf16x8*)&Pl[(wq * 32 + i * 16 + li) * 64
                                            + (((ks * 4 + quad) ^ (li & 7)) * 8)];
            #pragma unroll
            for (int j = 0; j < 4; ++j) {
                bf16x8 vf = *(const bf16x8*)&Vl[cur][(wm * 64 + j * 16 + li) * 64
                                                    + (((ks * 4 + quad) ^ (li & 7)) * 8)];
                #pragma unroll
                for (int i = 0; i < 2; ++i)
                    acc[i][j] = __builtin_amdgcn_mfma_f32_16x16x32_bf16(
                        af[i], vf, acc[i][j], 0, 0, 0);
            }
        }
        __builtin_amdgcn_s_setprio(0);

        // barrier 2: Pl / Vl[cur] reads done block-wide before next overwrite
        __builtin_amdgcn_sched_barrier(0);
        __builtin_amdgcn_s_barrier();
        __builtin_amdgcn_sched_barrier(0);
    }

    // l reduction: shfl over the 16 li lanes, then add the 4 wm-partner waves
    __syncthreads();
    if (tid < 64) ll[tid] = 0.f;
    __syncthreads();
    #pragma unroll
    for (int i = 0; i < 2; ++i)
        #pragma unroll
        for (int j = 0; j < 4; ++j) {
            float s = s4[i][j];
            s += __shfl_xor(s, 1, 64);
            s += __shfl_xor(s, 2, 64);
            s += __shfl_xor(s, 4, 64);
            s += __shfl_xor(s, 8, 64);
            if (li == 0) atomicAdd(&ll[wq * 32 + i * 16 + quad * 4 + j], s);
        }
    __syncthreads();

    const int isf32 = *flag;
    const float g = isf32 ? ((const float*)gptr)[0] : bf2f(((const ushort*)gptr)[0]);
    const ushort* xu = (const ushort*)x;
    const float*  xf = (const float*)x;
    ushort* ou = (ushort*)out;
    float*  of = (float*)out;
    #pragma unroll
    for (int i = 0; i < 2; ++i)
        #pragma unroll
        for (int jj = 0; jj < 4; ++jj) {
            int nl = wq * 32 + i * 16 + quad * 4 + jj;
            float inv = 1.f / ll[nl];
            size_t rowb = ((size_t)(b * N_ + q0 + nl)) * C_;
            #pragma unroll
            for (int j = 0; j < 4; ++j) {
                int cg = c0 + wm * 64 + j * 16 + li;
                size_t idx = rowb + cg;
                float xv  = isf32 ? xf[idx] : bf2f(xu[idx]);
                float val = g * (acc[i][j][jj] * inv) + xv;
                if (isf32) of[idx] = val; else ou[idx] = f2bf(val);
            }
        }
}

extern "C" void kernel_launch(void* const* d_in, const int* in_sizes, int n_in,
                              void* d_out, int out_size, void* d_ws, size_t ws_size,
                              hipStream_t stream) {
    (void)in_sizes; (void)n_in; (void)out_size; (void)ws_size;
    const void* x     = d_in[0];
    const void* Wq    = d_in[1];
    const void* bq    = d_in[2];
    const void* Wk    = d_in[3];
    const void* bk    = d_in[4];
    const void* Wv    = d_in[5];
    const void* bv    = d_in[6];
    const void* gamma = d_in[7];

    // workspace: flag(256B) + q(4M) + k(4M) + vt(32M) + xbf(32M) + wall(0.64M)
    int*    flag = (int*)d_ws;
    ushort* q    = (ushort*)((char*)d_ws + 256);
    ushort* kk   = q   + (size_t)B_ * N_ * D_;   // [B, N, 64] bf16
    ushort* vt   = kk  + (size_t)B_ * N_ * D_;   // [B, C, N] bf16
    ushort* xbf  = vt  + (size_t)B_ * C_ * N_;   // [M, C] bf16
    ushort* wall = xbf + (size_t)B_ * N_ * C_;   // [640, C] bf16 (Wq|Wk|Wv)

    probe_kernel<<<1, 64, 0, stream>>>(x, flag);
    convert_kernel<<<2048, 256, 0, stream>>>(x, Wq, Wk, Wv, xbf, wall, flag);

    // merged projection GEMM: M=32768, N=640 (64 q | 64 k | 512 v), K=512
    // grid: n-tile fastest -> 5 consecutive blocks share the A panel (L2 reuse)
    proj_all<<<dim3(640 / 128, B_ * N_ / 128), 256, 0, stream>>>(
        xbf, wall, bq, bk, bv, q, kk, vt, flag);

    attn_fused<<<dim3(N_ / 64, 2, B_), 512, 0, stream>>>(
        q, kk, vt, x, gamma, d_out, flag);
}

// Round 13
// 291.455 us; speedup vs baseline: 1.5361x; 1.0037x over previous
//
#include <hip/hip_runtime.h>
#include <hip/hip_bf16.h>

typedef __bf16 bf16x8 __attribute__((ext_vector_type(8)));
typedef float f32x4 __attribute__((ext_vector_type(4)));

#define B_ 16
#define N_ 2048
#define C_ 512
#define D_ 64

__device__ __forceinline__ float bf2f(ushort u) {
    union { uint i; float f; } w; w.i = ((uint)u) << 16; return w.f;
}
__device__ __forceinline__ ushort f2bf(float f) {
    union { float f; uint i; } w; w.f = f;
    uint u = w.i;
    u = (u + 0x7fffu + ((u >> 16) & 1u)) >> 16;
    return (ushort)u;
}
__device__ __forceinline__ __bf16 u2b(ushort u) {
    union { ushort s; __bf16 b; } w; w.s = u; return w.b;
}
__device__ __forceinline__ bf16x8 ld8u(const ushort* p) { return *(const bf16x8*)p; }
__device__ __forceinline__ bf16x8 ld8f(const float* p) {
    f32x4 a = *(const f32x4*)p;
    f32x4 b = *(const f32x4*)(p + 4);
    bf16x8 r;
    r[0] = u2b(f2bf(a[0])); r[1] = u2b(f2bf(a[1]));
    r[2] = u2b(f2bf(a[2])); r[3] = u2b(f2bf(a[3]));
    r[4] = u2b(f2bf(b[0])); r[5] = u2b(f2bf(b[1]));
    r[6] = u2b(f2bf(b[2])); r[7] = u2b(f2bf(b[3]));
    return r;
}

// async global->LDS, 16 B per lane; LDS dest = wave-uniform base + lane*16
__device__ __forceinline__ void gload16(const ushort* g, ushort* l) {
    __builtin_amdgcn_global_load_lds(
        (const __attribute__((address_space(1))) void*)g,
        (__attribute__((address_space(3))) void*)l, 16, 0, 0);
}

// Decide whether float tensors are stored as f32 or bf16 (bench: f32).
__global__ void probe_kernel(const void* x, int* flag) {
    int lane = threadIdx.x & 63;
    ushort u = ((const ushort*)x)[lane * 2];
    float v = fabsf(bf2f(u));
    bool sane = (v > 9.3e-10f) && (v < 1.1e9f) && (v == v);
    unsigned long long m = __ballot(sane);
    if (threadIdx.x == 0) *flag = (__popcll(m) >= 48) ? 0 : 1;  // 0=bf16, 1=f32
}

// One memory-bound pass: X -> xbf (bf16), pack [Wq|Wk|Wv] -> wall (bf16).
__global__ void convert_kernel(const void* __restrict__ X,
                               const void* __restrict__ Wq_,
                               const void* __restrict__ Wk_,
                               const void* __restrict__ Wv_,
                               ushort* __restrict__ xbf,
                               ushort* __restrict__ wall,
                               const int* __restrict__ flag) {
    const int isf32 = *flag;
    const size_t NX  = (size_t)B_ * N_ * C_;   // 16,777,216
    const size_t NWQ = (size_t)D_ * C_;        // 32,768
    const size_t NWV = (size_t)C_ * C_;        // 262,144
    const size_t total8 = (NX + 2 * NWQ + NWV) / 8;
    const size_t stride = (size_t)gridDim.x * blockDim.x;
    for (size_t v = (size_t)blockIdx.x * blockDim.x + threadIdx.x; v < total8; v += stride) {
        size_t e = v * 8;
        const void* src;
        size_t off;
        ushort* dst;
        if (e < NX)                { src = X;   off = e;                dst = xbf + e; }
        else if (e < NX + NWQ)     { src = Wq_; off = e - NX;           dst = wall + (e - NX); }
        else if (e < NX + 2 * NWQ) { src = Wk_; off = e - NX - NWQ;     dst = wall + (e - NX); }
        else                       { src = Wv_; off = e - NX - 2 * NWQ; dst = wall + (e - NX); }
        bf16x8 r = isf32 ? ld8f((const float*)src + off) : ld8u((const ushort*)src + off);
        *(bf16x8*)dst = r;
    }
}

// Merged Q+K+V projection, bf16-in, m97 structure (global_load_lds + XOR
// swizzle). v-blocks (n0>=128) use a transpose-in-LDS epilogue so the
// [b][c][m] vt store is fully coalesced (fixes 8x write amplification of
// the old 8B-at-4KB-stride ushort4 scatter).
#define TP_ 136   // transpose LDS pitch (ushorts): 16B-aligned rows, ~2-way banks
__launch_bounds__(256, 2)
__global__ void proj_all(const ushort* __restrict__ xbf,
                         const ushort* __restrict__ wall,
                         const void* __restrict__ bq_,
                         const void* __restrict__ bk_,
                         const void* __restrict__ bv_,
                         ushort* __restrict__ outq,
                         ushort* __restrict__ outk,
                         ushort* __restrict__ outv,
                         const int* __restrict__ flag) {
    // union: staging lA|lB (32 KB) vs transpose buffer T (34 KB)
    __shared__ __align__(16) char smem[128 * TP_ * 2];
    ushort* lA = (ushort*)smem;                 // [128*64]
    ushort* lB = lA + 128 * 64;                 // [128*64]
    ushort* T  = (ushort*)smem;                 // [128][TP_]

    const int tid  = threadIdx.x;
    const int wave = tid >> 6, lane = tid & 63;
    const int quad = lane >> 4, li = lane & 15;
    const int wr = (wave & 1) * 64;
    const int wc = (wave >> 1) * 64;
    const int n0 = blockIdx.x * 128;   // 5 n-tiles (fastest -> A-panel L2 reuse)
    const int m0 = blockIdx.y * 128;

    const int lrow8 = lane >> 3;
    const int lseg  = (lane & 7) ^ (lrow8 & 7);

    f32x4 acc[4][4];
    #pragma unroll
    for (int i = 0; i < 4; ++i)
        #pragma unroll
        for (int j = 0; j < 4; ++j) acc[i][j] = (f32x4){0.f, 0.f, 0.f, 0.f};

    for (int k0 = 0; k0 < C_; k0 += 64) {
        __syncthreads();
        #pragma unroll
        for (int i = 0; i < 4; ++i) {
            int rbase = wave * 32 + i * 8;
            gload16(xbf  + (size_t)(m0 + rbase + lrow8) * C_ + k0 + lseg * 8,
                    &lA[rbase * 64]);
            gload16(wall + (size_t)(n0 + rbase + lrow8) * C_ + k0 + lseg * 8,
                    &lB[rbase * 64]);
        }
        __syncthreads();
        #pragma unroll
        for (int ks = 0; ks < 2; ++ks) {
            bf16x8 af[4], bfr[4];
            #pragma unroll
            for (int i = 0; i < 4; ++i) {
                int row = wr + i * 16 + li;
                af[i] = *(const bf16x8*)&lA[row * 64 + (((ks * 4 + quad) ^ (li & 7)) * 8)];
            }
            #pragma unroll
            for (int j = 0; j < 4; ++j) {
                int row = wc + j * 16 + li;
                bfr[j] = *(const bf16x8*)&lB[row * 64 + (((ks * 4 + quad) ^ (li & 7)) * 8)];
            }
            #pragma unroll
            for (int i = 0; i < 4; ++i)
                #pragma unroll
                for (int j = 0; j < 4; ++j)
                    acc[i][j] = __builtin_amdgcn_mfma_f32_16x16x32_bf16(
                        af[i], bfr[j], acc[i][j], 0, 0, 0);
        }
    }

    const int isf32 = *flag;
    if (n0 == 0) {
        // q | k block: old per-element epilogue (8 MB, ~2x amp — negligible)
        #pragma unroll
        for (int j2 = 0; j2 < 4; ++j2) {
            int c = wc + j2 * 16 + li;
            float bv;
            if (!isf32) {
                bv = (c < 64) ? bf2f(((const ushort*)bq_)[c])
                              : bf2f(((const ushort*)bk_)[c - 64]);
            } else {
                bv = (c < 64) ? ((const float*)bq_)[c]
                              : ((const float*)bk_)[c - 64];
            }
            ushort* dst = (c < 64) ? outq : outk;
            int cl = c & 63;
            #pragma unroll
            for (int i = 0; i < 4; ++i)
                #pragma unroll
                for (int j = 0; j < 4; ++j) {
                    int m = m0 + wr + i * 16 + quad * 4 + j;
                    dst[(size_t)m * D_ + cl] = f2bf(acc[i][j2][j] + bv);
                }
        }
    } else {
        // v block: bias + bf16 into transposed LDS [c][m], then coalesced store
        __syncthreads();   // all waves done reading lA/lB before overwrite
        #pragma unroll
        for (int j2 = 0; j2 < 4; ++j2) {
            int cl = wc + j2 * 16 + li;               // local c 0..127
            int cv = (n0 - 128) + cl;                 // global v channel
            float bv = isf32 ? ((const float*)bv_)[cv]
                             : bf2f(((const ushort*)bv_)[cv]);
            #pragma unroll
            for (int i = 0; i < 4; ++i)
                #pragma unroll
                for (int j = 0; j < 4; ++j) {
                    int ml = wr + i * 16 + quad * 4 + j;   // local m 0..127
                    T[cl * TP_ + ml] = f2bf(acc[i][j2][j] + bv);
                }
        }
        __syncthreads();
        const int b      = m0 >> 11;          // batch (m0 multiple of 128)
        const int mlbase = m0 & (N_ - 1);
        const int cm  = tid & 15;             // 16B chunk within row
        const int cr  = tid >> 4;             // row group 0..15
        #pragma unroll
        for (int s = 0; s < 8; ++s) {
            int cl = s * 16 + cr;             // local c row
            int cv = (n0 - 128) + cl;
            bf16x8 vv = *(const bf16x8*)&T[cl * TP_ + cm * 8];
            *(bf16x8*)(outv + ((size_t)(b * C_ + cv)) * N_ + mlbase + cm * 8) = vv;
        }
    }
}

// Fused attention v3: double-buffered V with counted-vmcnt raw barriers
// (T3/T4-lite) + K register prefetch + setprio around PV (T5).
// (unchanged — measured 152 us, MfmaUtil 24%, Occ 41%, structural plateau)
__launch_bounds__(512, 4)
__global__ void attn_fused(const ushort* __restrict__ q,
                           const ushort* __restrict__ kk,
                           const ushort* __restrict__ vt,
                           const void* __restrict__ x,
                           const void* __restrict__ gptr,
                           void* __restrict__ out,
                           const int* __restrict__ flag) {
    __shared__ ushort Vl[2][256 * 64];   // 2 x 32 KB V tile (swizzled, rows=c)
    __shared__ ushort Pl[64 * 64];       //  8 KB P tile (swizzled)
    __shared__ float  ll[64];            // row sums

    const int tid  = threadIdx.x;
    const int wave = tid >> 6, lane = tid & 63;
    const int quad = lane >> 4, li = lane & 15;
    const int wq = wave & 1;          // q-half (32 rows)
    const int wm = wave >> 1;         // 16-wide m-range (QK) / 64-wide c-range (PV)
    const int b  = blockIdx.z;
    const int q0 = blockIdx.x * 64;
    const int c0 = blockIdx.y * 256;

    const ushort* kb = kk + (size_t)b * N_ * D_;
    const ushort* vb = vt + ((size_t)b * C_ + c0) * N_;

    // staging lane constants (pre-swizzled global source -> linear LDS dest)
    const int lrow8 = lane >> 3;               // 0..7
    const int lseg  = (lane & 7) ^ lrow8;      // XOR'd 16B granule

    // Q fragments: rows q0 + wq*32 + i*16 + li
    bf16x8 qf[2][2];
    #pragma unroll
    for (int i = 0; i < 2; ++i)
        #pragma unroll
        for (int ks = 0; ks < 2; ++ks)
            qf[i][ks] = ld8u(q + ((size_t)(b * N_ + q0 + wq * 32 + i * 16 + li)) * D_
                               + ks * 32 + quad * 8);

    f32x4 acc[2][4];   // O rows wq*32+i*16+quad*4+jj, cols c0+wm*64+j*16+li
    #pragma unroll
    for (int i = 0; i < 2; ++i)
        #pragma unroll
        for (int j = 0; j < 4; ++j) acc[i][j] = (f32x4){0.f, 0.f, 0.f, 0.f};

    f32x4 accp[2];     // P rows wq*32+i*16+quad*4+j, m col wm*16+li
    float s4[2][4];
    #pragma unroll
    for (int i = 0; i < 2; ++i) {
        accp[i] = (f32x4){0.f, 0.f, 0.f, 0.f};
        #pragma unroll
        for (int j = 0; j < 4; ++j) s4[i][j] = 0.f;
    }

    // prologue: stage V(0) -> Vl[0]; QK(0) with direct K loads; kreg = K(1)
    #pragma unroll
    for (int it = 0; it < 4; ++it) {
        int rbase = wave * 32 + it * 8;
        gload16(vb + (size_t)(rbase + lrow8) * N_ + lseg * 8, &Vl[0][rbase * 64]);
    }
    {
        bf16x8 k0 = ld8u(kb + (size_t)(wm * 16 + li) * D_ + quad * 8);
        bf16x8 k1 = ld8u(kb + (size_t)(wm * 16 + li) * D_ + 32 + quad * 8);
        accp[0] = __builtin_amdgcn_mfma_f32_16x16x32_bf16(qf[0][0], k0, accp[0], 0, 0, 0);
        accp[1] = __builtin_amdgcn_mfma_f32_16x16x32_bf16(qf[1][0], k0, accp[1], 0, 0, 0);
        accp[0] = __builtin_amdgcn_mfma_f32_16x16x32_bf16(qf[0][1], k1, accp[0], 0, 0, 0);
        accp[1] = __builtin_amdgcn_mfma_f32_16x16x32_bf16(qf[1][1], k1, accp[1], 0, 0, 0);
    }
    bf16x8 kreg0 = ld8u(kb + (size_t)(64 + wm * 16 + li) * D_ + quad * 8);
    bf16x8 kreg1 = ld8u(kb + (size_t)(64 + wm * 16 + li) * D_ + 32 + quad * 8);

    for (int t = 0; t < 32; ++t) {
        const int cur = t & 1;
        // (a) issue V(t+1) stage into the other buffer (async, not waited here)
        if (t < 31) {
            #pragma unroll
            for (int it = 0; it < 4; ++it) {
                int rbase = wave * 32 + it * 8;
                gload16(vb + (size_t)(rbase + lrow8) * N_ + (t + 1) * 64 + lseg * 8,
                        &Vl[cur ^ 1][rbase * 64]);
            }
        }
        // (b) P-write(t): exp(accp) -> swizzled LDS; accumulate row sums
        #pragma unroll
        for (int i = 0; i < 2; ++i)
            #pragma unroll
            for (int j = 0; j < 4; ++j) {
                int r = wq * 32 + i * 16 + quad * 4 + j;
                int m = wm * 16 + li;
                float e = __expf(fminf(accp[i][j], 60.f));
                s4[i][j] += e;
                *(__bf16*)&Pl[r * 64 + (((m >> 3) ^ (r & 7)) * 8) + (m & 7)] = (__bf16)e;
            }
        // (c) QK(t+1) from kreg; (d) prefetch kreg(t+2)
        if (t < 31) {
            f32x4 np0 = (f32x4){0.f, 0.f, 0.f, 0.f};
            f32x4 np1 = (f32x4){0.f, 0.f, 0.f, 0.f};
            np0 = __builtin_amdgcn_mfma_f32_16x16x32_bf16(qf[0][0], kreg0, np0, 0, 0, 0);
            np1 = __builtin_amdgcn_mfma_f32_16x16x32_bf16(qf[1][0], kreg0, np1, 0, 0, 0);
            np0 = __builtin_amdgcn_mfma_f32_16x16x32_bf16(qf[0][1], kreg1, np0, 0, 0, 0);
            np1 = __builtin_amdgcn_mfma_f32_16x16x32_bf16(qf[1][1], kreg1, np1, 0, 0, 0);
            if (t < 30) {
                kreg0 = ld8u(kb + (size_t)((t + 2) * 64 + wm * 16 + li) * D_ + quad * 8);
                kreg1 = ld8u(kb + (size_t)((t + 2) * 64 + wm * 16 + li) * D_ + 32 + quad * 8);
            }
            accp[0] = np0;
            accp[1] = np1;
        }
        // barrier 1: counted vmcnt leaves next-tile loads in flight
        if (t < 30)       asm volatile("s_waitcnt vmcnt(6) lgkmcnt(0)" ::: "memory");
        else if (t == 30) asm volatile("s_waitcnt vmcnt(4) lgkmcnt(0)" ::: "memory");
        else              asm volatile("s_waitcnt vmcnt(0) lgkmcnt(0)" ::: "memory");
        __builtin_amdgcn_sched_barrier(0);
        __builtin_amdgcn_s_barrier();
        __builtin_amdgcn_sched_barrier(0);

        // PV(t): A = P rows (wq half), B = V rows c (wm range)
        __builtin_amdgcn_s_setprio(1);
        #pragma unroll
        for (int ks = 0; ks < 2; ++ks) {
            bf16x8 af[2];
            #pragma unroll
            for (int i = 0; i < 2; ++i)
                af[i] = *(const bf16x8*)&Pl[(wq * 32 + i * 16 + li) * 64
                                            + (((ks * 4 + quad) ^ (li & 7)) * 8)];
            #pragma unroll
            for (int j = 0; j < 4; ++j) {
                bf16x8 vf = *(const bf16x8*)&Vl[cur][(wm * 64 + j * 16 + li) * 64
                                                    + (((ks * 4 + quad) ^ (li & 7)) * 8)];
                #pragma unroll
                for (int i = 0; i < 2; ++i)
                    acc[i][j] = __builtin_amdgcn_mfma_f32_16x16x32_bf16(
                        af[i], vf, acc[i][j], 0, 0, 0);
            }
        }
        __builtin_amdgcn_s_setprio(0);

        // barrier 2: Pl / Vl[cur] reads done block-wide before next overwrite
        __builtin_amdgcn_sched_barrier(0);
        __builtin_amdgcn_s_barrier();
        __builtin_amdgcn_sched_barrier(0);
    }

    // l reduction: shfl over the 16 li lanes, then add the 4 wm-partner waves
    __syncthreads();
    if (tid < 64) ll[tid] = 0.f;
    __syncthreads();
    #pragma unroll
    for (int i = 0; i < 2; ++i)
        #pragma unroll
        for (int j = 0; j < 4; ++j) {
            float s = s4[i][j];
            s += __shfl_xor(s, 1, 64);
            s += __shfl_xor(s, 2, 64);
            s += __shfl_xor(s, 4, 64);
            s += __shfl_xor(s, 8, 64);
            if (li == 0) atomicAdd(&ll[wq * 32 + i * 16 + quad * 4 + j], s);
        }
    __syncthreads();

    const int isf32 = *flag;
    const float g = isf32 ? ((const float*)gptr)[0] : bf2f(((const ushort*)gptr)[0]);
    const ushort* xu = (const ushort*)x;
    const float*  xf = (const float*)x;
    ushort* ou = (ushort*)out;
    float*  of = (float*)out;
    #pragma unroll
    for (int i = 0; i < 2; ++i)
        #pragma unroll
        for (int jj = 0; jj < 4; ++jj) {
            int nl = wq * 32 + i * 16 + quad * 4 + jj;
            float inv = 1.f / ll[nl];
            size_t rowb = ((size_t)(b * N_ + q0 + nl)) * C_;
            #pragma unroll
            for (int j = 0; j < 4; ++j) {
                int cg = c0 + wm * 64 + j * 16 + li;
                size_t idx = rowb + cg;
                float xv  = isf32 ? xf[idx] : bf2f(xu[idx]);
                float val = g * (acc[i][j][jj] * inv) + xv;
                if (isf32) of[idx] = val; else ou[idx] = f2bf(val);
            }
        }
}

extern "C" void kernel_launch(void* const* d_in, const int* in_sizes, int n_in,
                              void* d_out, int out_size, void* d_ws, size_t ws_size,
                              hipStream_t stream) {
    (void)in_sizes; (void)n_in; (void)out_size; (void)ws_size;
    const void* x     = d_in[0];
    const void* Wq    = d_in[1];
    const void* bq    = d_in[2];
    const void* Wk    = d_in[3];
    const void* bk    = d_in[4];
    const void* Wv    = d_in[5];
    const void* bv    = d_in[6];
    const void* gamma = d_in[7];

    // workspace: flag(256B) + q(4M) + k(4M) + vt(32M) + xbf(32M) + wall(0.64M)
    int*    flag = (int*)d_ws;
    ushort* q    = (ushort*)((char*)d_ws + 256);
    ushort* kk   = q   + (size_t)B_ * N_ * D_;   // [B, N, 64] bf16
    ushort* vt   = kk  + (size_t)B_ * N_ * D_;   // [B, C, N] bf16
    ushort* xbf  = vt  + (size_t)B_ * C_ * N_;   // [M, C] bf16
    ushort* wall = xbf + (size_t)B_ * N_ * C_;   // [640, C] bf16 (Wq|Wk|Wv)

    probe_kernel<<<1, 64, 0, stream>>>(x, flag);
    convert_kernel<<<2048, 256, 0, stream>>>(x, Wq, Wk, Wv, xbf, wall, flag);

    // merged projection GEMM: M=32768, N=640 (64 q | 64 k | 512 v), K=512
    proj_all<<<dim3(640 / 128, B_ * N_ / 128), 256, 0, stream>>>(
        xbf, wall, bq, bk, bv, q, kk, vt, flag);

    attn_fused<<<dim3(N_ / 64, 2, B_), 512, 0, stream>>>(
        q, kk, vt, x, gamma, d_out, flag);
}